// Round 8
// baseline (412.209 us; speedup 1.0000x reference)
//
#include <hip/hip_runtime.h>
#include <math.h>

#define NE 8
#define IN_C 192
#define HID 384
#define OUT_C 192
#define R_C 8
#define HW 16384
#define NPIX 65536
#define TN 64
#define PPB 16384   // pixels per image

typedef _Float16 h8_t __attribute__((ext_vector_type(8)));
typedef float f32x4 __attribute__((ext_vector_type(4)));

// A&S 7.1.26 erf (|abs err| <= 1.5e-7) -> exact-GELU within fp32 noise.
__device__ __forceinline__ float gelu_exact(float v) {
  float z  = v * 0.70710678118654752f;
  float az = fabsf(z);
  float t  = __builtin_amdgcn_rcpf(1.0f + 0.3275911f * az);
  float p  = ((((1.061405429f * t - 1.453152027f) * t + 1.421413741f) * t
               - 0.284496736f) * t + 0.254829592f) * t;
  float er = 1.0f - p * __expf(-z * z);
  er = copysignf(er, z);
  return 0.5f * v * (1.0f + er);
}

// ---------------------------------------------------------------------------
// Router: per-pixel 8 logits, top-2, 2-way softmax. Per-block LDS histogram +
// one global atomicAdd per (block, expert). Entry = p_local | (slot << 14).
// ---------------------------------------------------------------------------
__global__ __launch_bounds__(256) void router_kernel(
    const float* __restrict__ rin, const float* __restrict__ rW,
    const float* __restrict__ rb, int* __restrict__ counts,
    int* __restrict__ lists, float* __restrict__ gatev) {
  const int tid = threadIdx.x;
  const int pid = blockIdx.x * 256 + tid;
  const int img = pid >> 14;
  const int p = pid & (PPB - 1);

  __shared__ int lcount[NE];
  __shared__ int lbase[NE];
  if (tid < NE) lcount[tid] = 0;
  __syncthreads();

  const float* rbase = rin + (size_t)img * R_C * HW + p;
  float r[R_C];
#pragma unroll
  for (int c = 0; c < R_C; ++c) r[c] = rbase[(size_t)c * HW];
  float lg[NE];
#pragma unroll
  for (int e = 0; e < NE; ++e) {
    float s = rb[e];
#pragma unroll
    for (int c = 0; c < R_C; ++c) s += rW[e * R_C + c] * r[c];
    lg[e] = s;
  }
  int e0 = 0; float l0 = lg[0];
#pragma unroll
  for (int e = 1; e < NE; ++e) { if (lg[e] > l0) { l0 = lg[e]; e0 = e; } }
  int e1 = -1; float l1 = -3.4e38f;
#pragma unroll
  for (int e = 0; e < NE; ++e) {
    if (e != e0 && lg[e] > l1) { l1 = lg[e]; e1 = e; }
  }
  float ex  = expf(l1 - l0);
  float inv = 1.0f / (1.0f + ex);
  float g0 = inv, g1 = ex * inv;

  int pos0 = atomicAdd(&lcount[e0], 1);
  int pos1 = atomicAdd(&lcount[e1], 1);
  __syncthreads();
  if (tid < NE) lbase[tid] = atomicAdd(&counts[tid * 4 + img], lcount[tid]);
  __syncthreads();

  int i0 = (e0 * 4 + img) * PPB + lbase[e0] + pos0;
  lists[i0] = p;                 // slot 0
  gatev[i0] = g0;
  int i1 = (e1 * 4 + img) * PPB + lbase[e1] + pos1;
  lists[i1] = p | (1 << 14);     // slot 1
  gatev[i1] = g1;
}

// ---------------------------------------------------------------------------
// All-weight fp32 -> fp16 conversion in one launch.
// ---------------------------------------------------------------------------
#define N1_4 (NE * HID * IN_C / 4)
#define N2_4 (NE * HID * HID / 4)
#define N3_4 (NE * OUT_C * HID / 4)
__global__ __launch_bounds__(256) void cvt_all(
    const float* __restrict__ W1, const float* __restrict__ W2,
    const float* __restrict__ W3, _Float16* __restrict__ dst) {
  int i = blockIdx.x * 256 + threadIdx.x;
  if (i >= N1_4 + N2_4 + N3_4) return;
  const float* s; _Float16* d; int j = i;
  if (j < N1_4) { s = W1; d = dst; }
  else if (j < N1_4 + N2_4) { j -= N1_4; s = W2; d = dst + (size_t)NE * HID * IN_C; }
  else { j -= N1_4 + N2_4; s = W3; d = dst + (size_t)NE * (HID * IN_C + HID * HID); }
  float4 v = ((const float4*)s)[j];
  union { _Float16 h[4]; uint2 u; } cv;
  cv.h[0] = (_Float16)v.x; cv.h[1] = (_Float16)v.y;
  cv.h[2] = (_Float16)v.z; cv.h[3] = (_Float16)v.w;
  ((uint2*)d)[j] = cv.u;
}

// ---------------------------------------------------------------------------
// x transpose for one image: xb [192][16384] fp32 -> xt [16384][192] fp16.
// ---------------------------------------------------------------------------
__global__ __launch_bounds__(256) void xt_kernel(const float* __restrict__ xb,
                                                 _Float16* __restrict__ xt) {
  const int tid = threadIdx.x;
  const int p = blockIdx.x * 64 + (tid & 63);
  const int cq0 = tid >> 6;            // 0..3
#pragma unroll
  for (int cq = 0; cq < 6; ++cq) {
    int chq = cq * 4 + cq0;            // chunk 0..23 (8 channels each)
    union { _Float16 h[8]; uint4 u; } pk;
#pragma unroll
    for (int j = 0; j < 8; ++j)
      pk.h[j] = (_Float16)xb[(size_t)(chq * 8 + j) * HW + p];
    *(uint4*)(xt + (size_t)p * 192 + chq * 8) = pk.u;
  }
}

// ---------------------------------------------------------------------------
// MFMA helpers. B (activations) in LDS slot order [K/8][TN][8]: element (k,n)
// at ((k>>3)*TN + n)*8 + (k&7). A (weights) PRELOADED into VGPRs as a burst
// of independent 16B loads, pinned by sched_barrier(0) so hipcc can't sink
// them into the MFMA loop. Both operands use the identical (lane>>4,reg)->k
// map so any HW k-permutation cancels. C/D: col=lane&15, row=4*(lane>>4)+reg.
// ---------------------------------------------------------------------------
template<int NM, int NK>
__device__ __forceinline__ void wload(const _Float16* __restrict__ Wg, int lda,
                                      int m0, int mstride, int k0, int lane,
                                      h8_t (&w)[NM][NK]) {
  const int l15 = lane & 15, g = lane >> 4;
#pragma unroll
  for (int i = 0; i < NM; ++i)
#pragma unroll
    for (int kk = 0; kk < NK; ++kk)
      w[i][kk] = *(const h8_t*)(Wg + (size_t)(m0 + i * mstride + l15) * lda +
                                k0 + kk * 32 + g * 8);
}

template<int NM, int NK>
__device__ __forceinline__ void gemm_reg(const h8_t (&w)[NM][NK],
                                         const _Float16* __restrict__ Bsh, int kb0,
                                         f32x4 (&acc)[NM][4], int lane) {
  const int l15 = lane & 15, g = lane >> 4;
#pragma unroll
  for (int kk = 0; kk < NK; ++kk) {
    h8_t b[4];
#pragma unroll
    for (int nt = 0; nt < 4; ++nt)
      b[nt] = *(const h8_t*)(Bsh + ((size_t)((kb0 + kk) * 4 + g) * TN + nt * 16 + l15) * 8);
#pragma unroll
    for (int i = 0; i < NM; ++i)
#pragma unroll
      for (int nt = 0; nt < 4; ++nt)
        acc[i][nt] = __builtin_amdgcn_mfma_f32_16x16x32_f16(w[i][kk], b[nt], acc[i][nt], 0, 0, 0);
  }
}

// gelu + fp16 pack + store to LDS fragment layout; rows are LOCAL (m0 local).
template<int NM, int MSTRIDE>
__device__ __forceinline__ void act_store(f32x4 (&acc)[NM][4], const float* __restrict__ bias,
                                          _Float16* __restrict__ Dst, int m0, int lane) {
  const int l15 = lane & 15, g = lane >> 4;
#pragma unroll
  for (int i = 0; i < NM; ++i) {
    int rb = m0 + i * MSTRIDE + 4 * g;
    float4 bv = *(const float4*)(bias + rb);
#pragma unroll
    for (int nt = 0; nt < 4; ++nt) {
      int n = nt * 16 + l15;
      union { _Float16 h[4]; uint2 u; } cv;
      cv.h[0] = (_Float16)gelu_exact(acc[i][nt][0] + bv.x);
      cv.h[1] = (_Float16)gelu_exact(acc[i][nt][1] + bv.y);
      cv.h[2] = (_Float16)gelu_exact(acc[i][nt][2] + bv.z);
      cv.h[3] = (_Float16)gelu_exact(acc[i][nt][3] + bv.w);
      *(uint2*)(Dst + ((size_t)(rb >> 3) * TN + n) * 8 + (rb & 7)) = cv.u;
    }
  }
}

// gated y -> fp16, dense store into ybuf[(p*2+slot)*192 + c]
template<int NM>
__device__ __forceinline__ void ybuf_store(f32x4 (&acc)[NM][4], const float* __restrict__ bias,
                                           _Float16* __restrict__ ybuf,
                                           const int* __restrict__ pidsl,
                                           const float* __restrict__ pg,
                                           int npt, int m0, int lane) {
  const int l15 = lane & 15, g = lane >> 4;
#pragma unroll
  for (int nt = 0; nt < 4; ++nt) {
    int n = nt * 16 + l15;
    if (n >= npt) continue;
    float gt = pg[n];
    _Float16* yb = ybuf + pidsl[n];
#pragma unroll
    for (int i = 0; i < NM; ++i) {
      int rb = m0 + i * 16 + 4 * g;
      float4 bv = *(const float4*)(bias + rb);
      union { _Float16 h[4]; uint2 u; } cv;
      cv.h[0] = (_Float16)((acc[i][nt][0] + bv.x) * gt);
      cv.h[1] = (_Float16)((acc[i][nt][1] + bv.y) * gt);
      cv.h[2] = (_Float16)((acc[i][nt][2] + bv.z) * gt);
      cv.h[3] = (_Float16)((acc[i][nt][3] + bv.w) * gt);
      *(uint2*)(yb + rb) = cv.u;
    }
  }
}

// ---------------------------------------------------------------------------
// Phase 1: fused 3-layer expert MLP, 64-pixel tile, 8 waves. Weight bursts
// are software-pipelined ACROSS phases:
//   W1 under the x-gather; W2 (both K-halves) under act_store(H1)+barrier;
//   W3 (both K-halves) under act_store(H2)+barrier.
// sched_barrier(0) pins each burst's issue point. Peak ~220 VGPR, 2 w/SIMD.
// LDS: H1 48KB | RB 24KB (x) aliased by H2 48KB -> 96.75KB, 1 blk/CU.
// grid = (NE, tiles): bid%8==expert -> XCD L2 affinity for weight reads.
// ---------------------------------------------------------------------------
__global__ __launch_bounds__(512, 2) void moe_mfma_kernel(
    const _Float16* __restrict__ xt,
    const _Float16* __restrict__ W1h, const float* __restrict__ b1,
    const _Float16* __restrict__ W2h, const float* __restrict__ b2,
    const _Float16* __restrict__ W3h, const float* __restrict__ b3,
    const int* __restrict__ counts, const int* __restrict__ lists,
    const float* __restrict__ gatev, _Float16* __restrict__ ybuf, int img) {
  const int e = blockIdx.x;
  const int cnt = counts[e * 4 + img];
  const int start = blockIdx.y * TN;
  if (start >= cnt) return;
  const int npt = min(TN, cnt - start);

  __shared__ __align__(16) char smem[96 * 1024 + 768];
  _Float16* H1 = (_Float16*)smem;                  // [48][TN][8]
  _Float16* RB = (_Float16*)(smem + 48 * 1024);    // [24][TN][8] (x tile)
  _Float16* H2 = (_Float16*)(smem + 48 * 1024);    // [48][TN][8] aliases RB+
  int*   pp    = (int*)(smem + 96 * 1024);
  int*   pidsl = (int*)(smem + 96 * 1024 + 256);
  float* pg    = (float*)(smem + 96 * 1024 + 512);

  const int tid = threadIdx.x;
  const int lane = tid & 63;
  const int wid = tid >> 6;
  const int m1 = wid * 48;               // L1/L2 M-stripe base

  if (tid < TN) {
    int entry = 0; float g = 0.0f;
    if (tid < npt) {
      entry = lists[(e * 4 + img) * PPB + start + tid];
      g     = gatev[(e * 4 + img) * PPB + start + tid];
    }
    int p = entry & (PPB - 1);
    int slot = (entry >> 14) & 1;
    pp[tid] = p;
    pidsl[tid] = (p * 2 + slot) * 192;
    pg[tid] = g;
  }
  __syncthreads();

  const _Float16* W1e = W1h + (size_t)e * HID * IN_C;
  const _Float16* W2e = W2h + (size_t)e * HID * HID;
  const _Float16* W3e = W3h + (size_t)e * OUT_C * HID;

  // ---- W1 burst issued BEFORE the gather: hides under gather + barrier ----
  h8_t wA[3][6], wB[3][6];
  wload<3, 6>(W1e, IN_C, m1, 16, 0, lane, wA);
  __builtin_amdgcn_sched_barrier(0);

  // gather xt rows (fp16, 16B chunks) -> RB fragment layout
  for (int i = tid; i < 24 * TN; i += 512) {   // 3 iterations
    int n = i & 63;
    int c16 = i >> 6;
    uint4 v = {0, 0, 0, 0};
    if (n < npt) v = *(const uint4*)(xt + (size_t)pp[n] * 192 + c16 * 8);
    *(uint4*)(RB + ((size_t)c16 * TN + n) * 8) = v;
  }
  __syncthreads();

  f32x4 acc[3][4];
#pragma unroll
  for (int i = 0; i < 3; ++i)
#pragma unroll
    for (int nt = 0; nt < 4; ++nt) acc[i][nt] = (f32x4){0.f, 0.f, 0.f, 0.f};

  // ---- layer 1: H1 = gelu(W1 x + b1), K=192 ----
  gemm_reg<3, 6>(wA, RB, 0, acc, lane);
  // prefetch BOTH W2 K-halves under act_store + barrier
  wload<3, 6>(W2e, HID, m1, 16, 0, lane, wB);
  wload<3, 6>(W2e, HID, m1, 16, 192, lane, wA);
  __builtin_amdgcn_sched_barrier(0);
  act_store<3, 16>(acc, b1 + e * HID, H1, m1, lane);
  __syncthreads();

  // ---- layer 2: H2 = gelu(W2 h1 + b2), K=384 ----
#pragma unroll
  for (int i = 0; i < 3; ++i)
#pragma unroll
    for (int nt = 0; nt < 4; ++nt) acc[i][nt] = (f32x4){0.f, 0.f, 0.f, 0.f};
  gemm_reg<3, 6>(wB, H1, 0, acc, lane);
  gemm_reg<3, 6>(wA, H1, 6, acc, lane);

  // prefetch BOTH W3 K-halves under act_store + barrier.
  // Waves 0-3: 2 real stripes (mstride 16). Waves 4-7: single stripe loaded
  // twice (mstride 0) so shapes/barriers stay uniform; dup result discarded.
  const int m3  = (wid < 4) ? wid * 32 : 128 + (wid - 4) * 16;
  const int ms3 = (wid < 4) ? 16 : 0;
  h8_t w3a[2][6], w3b[2][6];
  wload<2, 6>(W3e, HID, m3, ms3, 0, lane, w3a);
  wload<2, 6>(W3e, HID, m3, ms3, 192, lane, w3b);
  __builtin_amdgcn_sched_barrier(0);
  act_store<3, 16>(acc, b2 + e * HID, H2, m1, lane);
  __syncthreads();

  // ---- layer 3: y = W3 h2 + b3, K=384, gated dense store to ybuf ----
  f32x4 acc3[2][4];
#pragma unroll
  for (int i = 0; i < 2; ++i)
#pragma unroll
    for (int nt = 0; nt < 4; ++nt) acc3[i][nt] = (f32x4){0.f, 0.f, 0.f, 0.f};
  gemm_reg<2, 6>(w3a, H2, 0, acc3, lane);
  gemm_reg<2, 6>(w3b, H2, 6, acc3, lane);

  if (wid < 4) {
    ybuf_store<2>(acc3, b3 + e * OUT_C, ybuf, pidsl, pg, npt, m3, lane);
  } else {
    ybuf_store<1>(*(f32x4(*)[1][4])&acc3[0], b3 + e * OUT_C, ybuf, pidsl, pg, npt, m3, lane);
  }
}

// ---------------------------------------------------------------------------
// Phase 2: per 64 contiguous pixels, sum the two gated slot results and write
// out[b][c][p] coalesced (fully overwrites -> no memset needed).
// ---------------------------------------------------------------------------
__global__ __launch_bounds__(256) void sum_kernel(
    const _Float16* __restrict__ ybuf, float* __restrict__ out, int img) {
  __shared__ float ys[TN][193];
  const int tid = threadIdx.x;
  const int p0 = blockIdx.x * TN;

  for (int t = tid; t < TN * 48; t += 256) {
    int p = t / 48, c4 = t % 48;
    const uint2* y0 = (const uint2*)(ybuf + ((size_t)(p0 + p) * 2) * 192) + c4;
    uint2 u0 = y0[0];
    uint2 u1 = y0[48];
    union { uint2 u; _Float16 h[4]; } a, b;
    a.u = u0; b.u = u1;
#pragma unroll
    for (int j = 0; j < 4; ++j)
      ys[p][c4 * 4 + j] = (float)a.h[j] + (float)b.h[j];
  }
  __syncthreads();

  float* ob = out + (size_t)img * OUT_C * HW + p0;
  for (int t = tid; t < OUT_C * TN; t += 256) {
    int c = t >> 6, p = t & (TN - 1);
    ob[(size_t)c * HW + p] = ys[p][c];
  }
}

extern "C" void kernel_launch(void* const* d_in, const int* in_sizes, int n_in,
                              void* d_out, int out_size, void* d_ws, size_t ws_size,
                              hipStream_t stream) {
  const float* x   = (const float*)d_in[0];
  const float* rin = (const float*)d_in[1];
  const float* rW  = (const float*)d_in[2];
  const float* rb  = (const float*)d_in[3];
  const float* W1  = (const float*)d_in[4];
  const float* b1  = (const float*)d_in[5];
  const float* W2  = (const float*)d_in[6];
  const float* b2  = (const float*)d_in[7];
  const float* W3  = (const float*)d_in[8];
  const float* b3  = (const float*)d_in[9];
  float* out = (float*)d_out;

  // ws: counts 1K | lists 2MB | gatev 2MB | W 9.2MB | ybuf 12.6MB | xt 6.3MB
  char* ws = (char*)d_ws;
  int*   counts = (int*)ws;
  int*   lists  = (int*)(ws + 1024);
  float* gatev  = (float*)(ws + 1024 + (size_t)NE * 4 * PPB * 4);
  _Float16* W1h = (_Float16*)(ws + 1024 + 2 * (size_t)NE * 4 * PPB * 4);
  _Float16* W2h = W1h + (size_t)NE * HID * IN_C;
  _Float16* W3h = W2h + (size_t)NE * HID * HID;
  _Float16* ybuf = W3h + (size_t)NE * OUT_C * HID;   // [PPB*2][192] fp16
  _Float16* xt = ybuf + (size_t)PPB * 2 * 192;       // [PPB][192] fp16

  hipMemsetAsync(counts, 0, NE * 4 * sizeof(int), stream);

  int ncv = N1_4 + N2_4 + N3_4;
  cvt_all<<<(ncv + 255) / 256, 256, 0, stream>>>(W1, W2, W3, W1h);

  router_kernel<<<NPIX / 256, 256, 0, stream>>>(rin, rW, rb, counts, lists, gatev);

  for (int b = 0; b < 4; ++b) {
    xt_kernel<<<PPB / 64, 256, 0, stream>>>(x + (size_t)b * IN_C * HW, xt);
    dim3 grid(NE, PPB / TN);   // cnt <= PPB per (e,img); inactive tiles exit
    moe_mfma_kernel<<<grid, 512, 0, stream>>>(xt, W1h, b1, W2h, b2, W3h, b3,
                                              counts, lists, gatev, ybuf, b);
    sum_kernel<<<PPB / TN, 256, 0, stream>>>(ybuf, out, b);
  }
}

// Round 9
// 350.339 us; speedup vs baseline: 1.1766x; 1.1766x over previous
//
#include <hip/hip_runtime.h>
#include <math.h>

#define NE 8
#define IN_C 192
#define HID 384
#define OUT_C 192
#define R_C 8
#define HW 16384
#define NPIX 65536
#define PPB 16384    // pixels per image
#define TNP 128      // pixels per moe block

typedef _Float16 h8_t __attribute__((ext_vector_type(8)));
typedef float f32x4 __attribute__((ext_vector_type(4)));

// A&S 7.1.26 erf (|abs err| <= 1.5e-7) -> exact-GELU within fp32 noise.
__device__ __forceinline__ float gelu_exact(float v) {
  float z  = v * 0.70710678118654752f;
  float az = fabsf(z);
  float t  = __builtin_amdgcn_rcpf(1.0f + 0.3275911f * az);
  float p  = ((((1.061405429f * t - 1.453152027f) * t + 1.421413741f) * t
               - 0.284496736f) * t + 0.254829592f) * t;
  float er = 1.0f - p * __expf(-z * z);
  er = copysignf(er, z);
  return 0.5f * v * (1.0f + er);
}

// ---------------------------------------------------------------------------
// Router: per-pixel 8 logits, top-2, 2-way softmax. Per-block LDS histogram +
// one global atomicAdd per (block, expert). Entry = p_local | (slot << 14).
// ---------------------------------------------------------------------------
__global__ __launch_bounds__(256) void router_kernel(
    const float* __restrict__ rin, const float* __restrict__ rW,
    const float* __restrict__ rb, int* __restrict__ counts,
    int* __restrict__ lists, float* __restrict__ gatev) {
  const int tid = threadIdx.x;
  const int pid = blockIdx.x * 256 + tid;
  const int img = pid >> 14;
  const int p = pid & (PPB - 1);

  __shared__ int lcount[NE];
  __shared__ int lbase[NE];
  if (tid < NE) lcount[tid] = 0;
  __syncthreads();

  const float* rbase = rin + (size_t)img * R_C * HW + p;
  float r[R_C];
#pragma unroll
  for (int c = 0; c < R_C; ++c) r[c] = rbase[(size_t)c * HW];
  float lg[NE];
#pragma unroll
  for (int e = 0; e < NE; ++e) {
    float s = rb[e];
#pragma unroll
    for (int c = 0; c < R_C; ++c) s += rW[e * R_C + c] * r[c];
    lg[e] = s;
  }
  int e0 = 0; float l0 = lg[0];
#pragma unroll
  for (int e = 1; e < NE; ++e) { if (lg[e] > l0) { l0 = lg[e]; e0 = e; } }
  int e1 = -1; float l1 = -3.4e38f;
#pragma unroll
  for (int e = 0; e < NE; ++e) {
    if (e != e0 && lg[e] > l1) { l1 = lg[e]; e1 = e; }
  }
  float ex  = expf(l1 - l0);
  float inv = 1.0f / (1.0f + ex);
  float g0 = inv, g1 = ex * inv;

  int pos0 = atomicAdd(&lcount[e0], 1);
  int pos1 = atomicAdd(&lcount[e1], 1);
  __syncthreads();
  if (tid < NE) lbase[tid] = atomicAdd(&counts[tid * 4 + img], lcount[tid]);
  __syncthreads();

  int i0 = (e0 * 4 + img) * PPB + lbase[e0] + pos0;
  lists[i0] = p;
  gatev[i0] = g0;
  int i1 = (e1 * 4 + img) * PPB + lbase[e1] + pos1;
  lists[i1] = p | (1 << 14);
  gatev[i1] = g1;
}

// ---------------------------------------------------------------------------
// Weight transforms: fp32 row-major -> fp16 A-fragment slot-order chunks.
// Chunk layout (one kk=32 step): [g 0..3][m 0..MTOT-1][j 0..7],
// element (m, k0 + 8g + j). Staging is then a LINEAR copy and LDS ds_reads
// are conflict-free (lanes read consecutive m at 16B stride).
//   W1: [e][h 0..1][c 0..5][g][m 0..191][j]   (row = h*192+m, col = 32c+8g+j)
//   W2: [e][kh 0..1][c 0..5][g][m 0..383][j]  (row = m, col = kh*192+32c+8g+j)
//   W3: [e][c 0..11][g][m 0..191][j]          (row = m, col = 32c+8g+j)
// ---------------------------------------------------------------------------
__global__ __launch_bounds__(256) void cvt_w1(const float* __restrict__ W,
                                              _Float16* __restrict__ d) {
  int t = blockIdx.x * 256 + threadIdx.x;
  const int QE = 73728 / 4;
  if (t >= NE * QE) return;
  int e = t / QE, qq = t % QE;
  int j4 = qq & 1, q = qq >> 1;
  int m = q % 192; q /= 192;
  int g = q % 4;   q /= 4;
  int c = q % 6;   q /= 6;
  int h = q;
  int row = h * 192 + m, col = 32 * c + 8 * g + 4 * j4;
  float4 v = *(const float4*)(W + (size_t)e * 73728 + (size_t)row * 192 + col);
  union { _Float16 h4[4]; uint2 u; } cv;
  cv.h4[0] = (_Float16)v.x; cv.h4[1] = (_Float16)v.y;
  cv.h4[2] = (_Float16)v.z; cv.h4[3] = (_Float16)v.w;
  ((uint2*)d)[t] = cv.u;
}

__global__ __launch_bounds__(256) void cvt_w2(const float* __restrict__ W,
                                              _Float16* __restrict__ d) {
  int t = blockIdx.x * 256 + threadIdx.x;
  const int QE = 147456 / 4;
  if (t >= NE * QE) return;
  int e = t / QE, qq = t % QE;
  int j4 = qq & 1, q = qq >> 1;
  int m = q % 384; q /= 384;
  int g = q % 4;   q /= 4;
  int c = q % 6;   q /= 6;
  int kh = q;
  int col = kh * 192 + 32 * c + 8 * g + 4 * j4;
  float4 v = *(const float4*)(W + (size_t)e * 147456 + (size_t)m * 384 + col);
  union { _Float16 h4[4]; uint2 u; } cv;
  cv.h4[0] = (_Float16)v.x; cv.h4[1] = (_Float16)v.y;
  cv.h4[2] = (_Float16)v.z; cv.h4[3] = (_Float16)v.w;
  ((uint2*)d)[t] = cv.u;
}

__global__ __launch_bounds__(256) void cvt_w3(const float* __restrict__ W,
                                              _Float16* __restrict__ d) {
  int t = blockIdx.x * 256 + threadIdx.x;
  const int QE = 73728 / 4;
  if (t >= NE * QE) return;
  int e = t / QE, qq = t % QE;
  int j4 = qq & 1, q = qq >> 1;
  int m = q % 192; q /= 192;
  int g = q % 4;   q /= 4;
  int c = q;                       // 0..11
  int col = 32 * c + 8 * g + 4 * j4;
  float4 v = *(const float4*)(W + (size_t)e * 73728 + (size_t)m * 384 + col);
  union { _Float16 h4[4]; uint2 u; } cv;
  cv.h4[0] = (_Float16)v.x; cv.h4[1] = (_Float16)v.y;
  cv.h4[2] = (_Float16)v.z; cv.h4[3] = (_Float16)v.w;
  ((uint2*)d)[t] = cv.u;
}

// ---------------------------------------------------------------------------
// x transpose for one image: xb [192][16384] fp32 -> xt [16384][192] fp16.
// ---------------------------------------------------------------------------
__global__ __launch_bounds__(256) void xt_kernel(const float* __restrict__ xb,
                                                 _Float16* __restrict__ xt) {
  const int tid = threadIdx.x;
  const int p = blockIdx.x * 64 + (tid & 63);
  const int cq0 = tid >> 6;
#pragma unroll
  for (int cq = 0; cq < 6; ++cq) {
    int chq = cq * 4 + cq0;
    union { _Float16 h[8]; uint4 u; } pk;
#pragma unroll
    for (int j = 0; j < 8; ++j)
      pk.h[j] = (_Float16)xb[(size_t)(chq * 8 + j) * HW + p];
    *(uint4*)(xt + (size_t)p * 192 + chq * 8) = pk.u;
  }
}

// ---------------------------------------------------------------------------
// Weight staging: linear chunk copy global -> LDS via global_load_lds.
// LDS dest = wave-uniform base (+ lane*16 added by HW); bytes = 12288|24576.
// ---------------------------------------------------------------------------
__device__ __forceinline__ void stage_chunk(const _Float16* __restrict__ src,
                                            char* lds, int bytes, int tid) {
  const int wid = tid >> 6;
  const char* g = (const char*)src;
  for (int off = 0; off + 8192 <= bytes; off += 8192) {
    __builtin_amdgcn_global_load_lds(
        (const __attribute__((address_space(1))) void*)(g + off + tid * 16),
        (__attribute__((address_space(3))) void*)(lds + off + wid * 1024),
        16, 0, 0);
  }
  if (bytes & 8191) {
    int off = bytes & ~8191;
    if (wid < 4)
      __builtin_amdgcn_global_load_lds(
          (const __attribute__((address_space(1))) void*)(g + off + tid * 16),
          (__attribute__((address_space(3))) void*)(lds + off + wid * 1024),
          16, 0, 0);
  }
}

// 2-phase pipeline over a layer's chunks: stage c+1 (or next layer's chunk 0)
// while computing c; per-chunk __syncthreads drains the DMA (vmcnt before
// s_barrier) so chunk c+1 is ready next iteration.
template <typename F>
__device__ __forceinline__ void pipe(const _Float16* __restrict__ src, int nc, int cb,
                                     const _Float16* __restrict__ nsrc, int ncb,
                                     int& cc, char* stg0, char* stg1, int tid, F comp) {
  for (int c = 0; c < nc; ++c) {
    char* nslot = ((cc + 1) & 1) ? stg1 : stg0;
    if (c + 1 < nc)      stage_chunk(src + (size_t)(c + 1) * (cb >> 1), nslot, cb, tid);
    else if (nsrc)       stage_chunk(nsrc, nslot, ncb, tid);
    comp(c, (const _Float16*)((cc & 1) ? stg1 : stg0));
    ++cc;
    __syncthreads();
  }
}

// One kk=32 MFMA step: A from staged chunk [g][MTOT][8], B from LDS slot
// order [k>>3][TNP][8]. Identical (lane>>4, j)->k map on both sides; C/D:
// col=lane&15, row=4*(lane>>4)+reg (HW-verified).
template <int NM, int NT, int MTOT>
__device__ __forceinline__ void mfma_chunk(const _Float16* __restrict__ A,
                                           const _Float16* __restrict__ B, int kb4,
                                           int m0, int nt0,
                                           f32x4 (&acc)[NM][NT], int lane) {
  const int l15 = lane & 15, g = lane >> 4;
  h8_t a[NM], b[NT];
#pragma unroll
  for (int i = 0; i < NM; ++i)
    a[i] = *(const h8_t*)(A + ((size_t)g * MTOT + m0 + i * 16 + l15) * 8);
#pragma unroll
  for (int t = 0; t < NT; ++t)
    b[t] = *(const h8_t*)(B + (((size_t)(kb4 + g) * TNP) + (nt0 + t) * 16 + l15) * 8);
#pragma unroll
  for (int i = 0; i < NM; ++i)
#pragma unroll
    for (int t = 0; t < NT; ++t)
      acc[i][t] = __builtin_amdgcn_mfma_f32_16x16x32_f16(a[i], b[t], acc[i][t], 0, 0, 0);
}

// gelu + fp16 pack + store to LDS slot order; m0/bias indices are LOCAL.
template <int NM, int NT>
__device__ __forceinline__ void act_store(f32x4 (&acc)[NM][NT], const float* __restrict__ bias,
                                          _Float16* __restrict__ Dst, int m0, int nt0, int lane) {
  const int l15 = lane & 15, g = lane >> 4;
#pragma unroll
  for (int i = 0; i < NM; ++i) {
    int rb = m0 + i * 16 + 4 * g;
    float4 bv = *(const float4*)(bias + rb);
#pragma unroll
    for (int t = 0; t < NT; ++t) {
      int n = (nt0 + t) * 16 + l15;
      union { _Float16 h[4]; uint2 u; } cv;
      cv.h[0] = (_Float16)gelu_exact(acc[i][t][0] + bv.x);
      cv.h[1] = (_Float16)gelu_exact(acc[i][t][1] + bv.y);
      cv.h[2] = (_Float16)gelu_exact(acc[i][t][2] + bv.z);
      cv.h[3] = (_Float16)gelu_exact(acc[i][t][3] + bv.w);
      *(uint2*)(Dst + (((size_t)(rb >> 3) * TNP) + n) * 8 + (rb & 7)) = cv.u;
    }
  }
}

// gated y -> fp16, dense store into ybuf[(p*2+slot)*192 + c]
template <int NM, int NT>
__device__ __forceinline__ void ybuf_store(f32x4 (&acc)[NM][NT], const float* __restrict__ bias,
                                           _Float16* __restrict__ ybuf,
                                           const int* __restrict__ pidsl,
                                           const float* __restrict__ pg,
                                           int npt, int m0, int nt0, int lane) {
  const int l15 = lane & 15, g = lane >> 4;
#pragma unroll
  for (int t = 0; t < NT; ++t) {
    int n = (nt0 + t) * 16 + l15;
    if (n >= npt) continue;
    float gt = pg[n];
    _Float16* yb = ybuf + pidsl[n];
#pragma unroll
    for (int i = 0; i < NM; ++i) {
      int rb = m0 + i * 16 + 4 * g;
      float4 bv = *(const float4*)(bias + rb);
      union { _Float16 h[4]; uint2 u; } cv;
      cv.h[0] = (_Float16)((acc[i][t][0] + bv.x) * gt);
      cv.h[1] = (_Float16)((acc[i][t][1] + bv.y) * gt);
      cv.h[2] = (_Float16)((acc[i][t][2] + bv.z) * gt);
      cv.h[3] = (_Float16)((acc[i][t][3] + bv.w) * gt);
      *(uint2*)(yb + rb) = cv.u;
    }
  }
}

// ---------------------------------------------------------------------------
// Fused 3-layer MLP, 128-pixel tile, 8 waves, weights streamed through a
// 2x24KB LDS double-buffer (global_load_lds). Phases:
//   L1 M-half0 -> H1a | L2 K-part0 (acc2 +=) | L1 M-half1 -> H1a |
//   L2 K-part1 | gelu(acc2) -> H2 | L3 over H2 -> gated ybuf store.
// LDS: XB 48K @0 | H1a 48K @48K | H2 96K @0 (aliases) | stage 48K @96K.
// grid = (NE, PPB/TNP): linear bid%8==expert -> XCD L2 affinity.
// ---------------------------------------------------------------------------
__global__ __launch_bounds__(512, 2) void moe_mfma_kernel(
    const _Float16* __restrict__ xt,
    const _Float16* __restrict__ W1s, const float* __restrict__ b1,
    const _Float16* __restrict__ W2s, const float* __restrict__ b2,
    const _Float16* __restrict__ W3s, const float* __restrict__ b3,
    const int* __restrict__ counts, const int* __restrict__ lists,
    const float* __restrict__ gatev, _Float16* __restrict__ ybuf, int img) {
  const int e = blockIdx.x;
  const int cnt = counts[e * 4 + img];
  const int start = blockIdx.y * TNP;
  if (start >= cnt) return;
  const int npt = min(TNP, cnt - start);

  __shared__ __align__(16) char smem[147456 + 1536];
  _Float16* XB  = (_Float16*)smem;                 // [24][128][8]
  _Float16* H1a = (_Float16*)(smem + 49152);       // [24][128][8]
  _Float16* H2  = (_Float16*)smem;                 // [48][128][8] aliases both
  char* STG0 = smem + 98304;
  char* STG1 = smem + 122880;
  int*   pp    = (int*)(smem + 147456);
  int*   pidsl = (int*)(smem + 147456 + 512);
  float* pg    = (float*)(smem + 147456 + 1024);

  const int tid = threadIdx.x;
  const int lane = tid & 63;
  const int wid = tid >> 6;
  // wave roles
  const int m1 = (wid >> 1) * 48, n1 = (wid & 1) * 4;  // L1: 4Mx2N
  const int m2 = wid * 48;                              // L2: 8M
  const int m3 = (wid >> 2) * 96, n3 = (wid & 3) * 2;   // L3: 2Mx4N

  // weight bases (slot-order chunk layouts)
  const _Float16* W1e = W1s + (size_t)e * 73728;
  const _Float16* W2e = W2s + (size_t)e * 147456;
  const _Float16* W3e = W3s + (size_t)e * 73728;
  const _Float16* W1h0 = W1e;
  const _Float16* W1h1 = W1e + 36864;
  const _Float16* W2k0 = W2e;
  const _Float16* W2k1 = W2e + 73728;

  // prologue: stage first W1 chunk while lists/gather run
  int cc = 0;
  stage_chunk(W1h0, STG0, 12288, tid);

  if (tid < TNP) {
    int entry = 0; float g = 0.0f;
    if (tid < npt) {
      entry = lists[(e * 4 + img) * PPB + start + tid];
      g     = gatev[(e * 4 + img) * PPB + start + tid];
    }
    int p = entry & (PPB - 1);
    int slot = (entry >> 14) & 1;
    pp[tid] = p;
    pidsl[tid] = (p * 2 + slot) * 192;
    pg[tid] = g;
  }
  __syncthreads();

  // gather xt rows -> XB slot order
  for (int i = tid; i < 24 * TNP; i += 512) {   // 6 iterations
    int n = i & (TNP - 1);
    int c16 = i >> 7;
    uint4 v = {0, 0, 0, 0};
    if (n < npt) v = *(const uint4*)(xt + (size_t)pp[n] * 192 + c16 * 8);
    *(uint4*)(XB + ((size_t)c16 * TNP + n) * 8) = v;
  }
  __syncthreads();

  f32x4 acc2[3][8];
#pragma unroll
  for (int i = 0; i < 3; ++i)
#pragma unroll
    for (int t = 0; t < 8; ++t) acc2[i][t] = (f32x4){0.f, 0.f, 0.f, 0.f};
  f32x4 acc1[3][4];

  // ---- L1 half 0 ----
#pragma unroll
  for (int i = 0; i < 3; ++i)
#pragma unroll
    for (int t = 0; t < 4; ++t) acc1[i][t] = (f32x4){0.f, 0.f, 0.f, 0.f};
  pipe(W1h0, 6, 12288, W2k0, 24576, cc, STG0, STG1, tid,
       [&](int c, const _Float16* A) {
         mfma_chunk<3, 4, 192>(A, XB, c * 4, m1, n1, acc1, lane);
       });
  act_store<3, 4>(acc1, b1 + e * HID, H1a, m1, n1, lane);
  __syncthreads();

  // ---- L2 K-part 0 ----
  pipe(W2k0, 6, 24576, W1h1, 12288, cc, STG0, STG1, tid,
       [&](int c, const _Float16* A) {
         mfma_chunk<3, 8, 384>(A, H1a, c * 4, m2, 0, acc2, lane);
       });

  // ---- L1 half 1 ----
#pragma unroll
  for (int i = 0; i < 3; ++i)
#pragma unroll
    for (int t = 0; t < 4; ++t) acc1[i][t] = (f32x4){0.f, 0.f, 0.f, 0.f};
  pipe(W1h1, 6, 12288, W2k1, 24576, cc, STG0, STG1, tid,
       [&](int c, const _Float16* A) {
         mfma_chunk<3, 4, 192>(A, XB, c * 4, m1, n1, acc1, lane);
       });
  act_store<3, 4>(acc1, b1 + e * HID + 192, H1a, m1, n1, lane);
  __syncthreads();

  // ---- L2 K-part 1 ----
  pipe(W2k1, 6, 24576, W3e, 12288, cc, STG0, STG1, tid,
       [&](int c, const _Float16* A) {
         mfma_chunk<3, 8, 384>(A, H1a, c * 4, m2, 0, acc2, lane);
       });

  // ---- gelu(acc2) -> H2 (overwrites XB+H1a region) ----
  act_store<3, 8>(acc2, b2 + e * HID, H2, m2, 0, lane);
  __syncthreads();

  // ---- L3 over H2, K=384 (12 chunks) ----
  f32x4 acc3[6][2];
#pragma unroll
  for (int i = 0; i < 6; ++i)
#pragma unroll
    for (int t = 0; t < 2; ++t) acc3[i][t] = (f32x4){0.f, 0.f, 0.f, 0.f};
  pipe(W3e, 12, 12288, (const _Float16*)nullptr, 0, cc, STG0, STG1, tid,
       [&](int c, const _Float16* A) {
         mfma_chunk<6, 2, 192>(A, H2, c * 4, m3, n3, acc3, lane);
       });

  ybuf_store<6, 2>(acc3, b3 + e * OUT_C, ybuf, pidsl, pg, npt, m3, n3, lane);
}

// ---------------------------------------------------------------------------
// Phase 2: per 64 contiguous pixels, sum the two gated slot results and write
// out[b][c][p] coalesced (fully overwrites -> no memset needed).
// ---------------------------------------------------------------------------
#define SN 64
__global__ __launch_bounds__(256) void sum_kernel(
    const _Float16* __restrict__ ybuf, float* __restrict__ out, int img) {
  __shared__ float ys[SN][193];
  const int tid = threadIdx.x;
  const int p0 = blockIdx.x * SN;

  for (int t = tid; t < SN * 48; t += 256) {
    int p = t / 48, c4 = t % 48;
    const uint2* y0 = (const uint2*)(ybuf + ((size_t)(p0 + p) * 2) * 192) + c4;
    uint2 u0 = y0[0];
    uint2 u1 = y0[48];
    union { uint2 u; _Float16 h[4]; } a, b;
    a.u = u0; b.u = u1;
#pragma unroll
    for (int j = 0; j < 4; ++j)
      ys[p][c4 * 4 + j] = (float)a.h[j] + (float)b.h[j];
  }
  __syncthreads();

  float* ob = out + (size_t)img * OUT_C * HW + p0;
  for (int t = tid; t < OUT_C * SN; t += 256) {
    int c = t >> 6, p = t & (SN - 1);
    ob[(size_t)c * HW + p] = ys[p][c];
  }
}

extern "C" void kernel_launch(void* const* d_in, const int* in_sizes, int n_in,
                              void* d_out, int out_size, void* d_ws, size_t ws_size,
                              hipStream_t stream) {
  const float* x   = (const float*)d_in[0];
  const float* rin = (const float*)d_in[1];
  const float* rW  = (const float*)d_in[2];
  const float* rb  = (const float*)d_in[3];
  const float* W1  = (const float*)d_in[4];
  const float* b1  = (const float*)d_in[5];
  const float* W2  = (const float*)d_in[6];
  const float* b2  = (const float*)d_in[7];
  const float* W3  = (const float*)d_in[8];
  const float* b3  = (const float*)d_in[9];
  float* out = (float*)d_out;

  // ws: counts 1K | lists 2MB | gatev 2MB | W 4.7MB | ybuf 12.6MB | xt 6.3MB
  char* ws = (char*)d_ws;
  int*   counts = (int*)ws;
  int*   lists  = (int*)(ws + 1024);
  float* gatev  = (float*)(ws + 1024 + (size_t)NE * 4 * PPB * 4);
  _Float16* W1s = (_Float16*)(ws + 1024 + 2 * (size_t)NE * 4 * PPB * 4);
  _Float16* W2s = W1s + (size_t)NE * HID * IN_C;
  _Float16* W3s = W2s + (size_t)NE * HID * HID;
  _Float16* ybuf = W3s + (size_t)NE * OUT_C * HID;   // [PPB*2][192] fp16
  _Float16* xt = ybuf + (size_t)PPB * 2 * 192;       // [PPB][192] fp16

  hipMemsetAsync(counts, 0, NE * 4 * sizeof(int), stream);

  cvt_w1<<<(NE * 73728 / 4 + 255) / 256, 256, 0, stream>>>(W1, W1s);
  cvt_w2<<<(NE * 147456 / 4 + 255) / 256, 256, 0, stream>>>(W2, W2s);
  cvt_w3<<<(NE * 73728 / 4 + 255) / 256, 256, 0, stream>>>(W3, W3s);

  router_kernel<<<NPIX / 256, 256, 0, stream>>>(rin, rW, rb, counts, lists, gatev);

  for (int b = 0; b < 4; ++b) {
    xt_kernel<<<PPB / 64, 256, 0, stream>>>(x + (size_t)b * IN_C * HW, xt);
    dim3 grid(NE, PPB / TNP);
    moe_mfma_kernel<<<grid, 512, 0, stream>>>(xt, W1s, b1, W2s, b2, W3s, b3,
                                              counts, lists, gatev, ybuf, b);
    sum_kernel<<<PPB / SN, 256, 0, stream>>>(ybuf, out, b);
  }
}

// Round 10
// 318.250 us; speedup vs baseline: 1.2952x; 1.1008x over previous
//
#include <hip/hip_runtime.h>
#include <math.h>

#define NE 8
#define IN_C 192
#define HID 384
#define OUT_C 192
#define R_C 8
#define HW 16384
#define NPIX 65536
#define PPB 16384    // pixels per image
#define TN 64        // pixels per moe block

typedef _Float16 h8_t __attribute__((ext_vector_type(8)));
typedef float f32x4 __attribute__((ext_vector_type(4)));

// A&S 7.1.26 erf (|abs err| <= 1.5e-7) -> exact-GELU within fp32 noise.
__device__ __forceinline__ float gelu_exact(float v) {
  float z  = v * 0.70710678118654752f;
  float az = fabsf(z);
  float t  = __builtin_amdgcn_rcpf(1.0f + 0.3275911f * az);
  float p  = ((((1.061405429f * t - 1.453152027f) * t + 1.421413741f) * t
               - 0.284496736f) * t + 0.254829592f) * t;
  float er = 1.0f - p * __expf(-z * z);
  er = copysignf(er, z);
  return 0.5f * v * (1.0f + er);
}

// ---------------------------------------------------------------------------
// Router: per-pixel 8 logits, top-2, 2-way softmax. Per-block LDS histogram +
// one global atomicAdd per (block, expert). Entry = p_local | (slot << 14).
// ---------------------------------------------------------------------------
__global__ __launch_bounds__(256) void router_kernel(
    const float* __restrict__ rin, const float* __restrict__ rW,
    const float* __restrict__ rb, int* __restrict__ counts,
    int* __restrict__ lists, float* __restrict__ gatev) {
  const int tid = threadIdx.x;
  const int pid = blockIdx.x * 256 + tid;
  const int img = pid >> 14;
  const int p = pid & (PPB - 1);

  __shared__ int lcount[NE];
  __shared__ int lbase[NE];
  if (tid < NE) lcount[tid] = 0;
  __syncthreads();

  const float* rbase = rin + (size_t)img * R_C * HW + p;
  float r[R_C];
#pragma unroll
  for (int c = 0; c < R_C; ++c) r[c] = rbase[(size_t)c * HW];
  float lg[NE];
#pragma unroll
  for (int e = 0; e < NE; ++e) {
    float s = rb[e];
#pragma unroll
    for (int c = 0; c < R_C; ++c) s += rW[e * R_C + c] * r[c];
    lg[e] = s;
  }
  int e0 = 0; float l0 = lg[0];
#pragma unroll
  for (int e = 1; e < NE; ++e) { if (lg[e] > l0) { l0 = lg[e]; e0 = e; } }
  int e1 = -1; float l1 = -3.4e38f;
#pragma unroll
  for (int e = 0; e < NE; ++e) {
    if (e != e0 && lg[e] > l1) { l1 = lg[e]; e1 = e; }
  }
  float ex  = expf(l1 - l0);
  float inv = 1.0f / (1.0f + ex);
  float g0 = inv, g1 = ex * inv;

  int pos0 = atomicAdd(&lcount[e0], 1);
  int pos1 = atomicAdd(&lcount[e1], 1);
  __syncthreads();
  if (tid < NE) lbase[tid] = atomicAdd(&counts[tid * 4 + img], lcount[tid]);
  __syncthreads();

  int i0 = (e0 * 4 + img) * PPB + lbase[e0] + pos0;
  lists[i0] = p;
  gatev[i0] = g0;
  int i1 = (e1 * 4 + img) * PPB + lbase[e1] + pos1;
  lists[i1] = p | (1 << 14);
  gatev[i1] = g1;
}

// ---------------------------------------------------------------------------
// Weight transforms -> fp16 A-fragment slot-order, UNIFORM 12KB chunks
// [g:4][m:192][j:8] (element (m, k0+8g+j)). Staging = linear copy;
// ds_reads conflict-light.
//   W1: [e][h:2][c:6] chunk    (row = h*192+m, col = 32c+8g+j)
//   W2: [e][kh:2][c:6][mh:2]   (row = mh*192+m, col = kh*192+32c+8g+j)
//   W3: [e][c:12]              (row = m, col = 32c+8g+j)
// ---------------------------------------------------------------------------
__global__ __launch_bounds__(256) void cvt_w1(const float* __restrict__ W,
                                              _Float16* __restrict__ d) {
  int t = blockIdx.x * 256 + threadIdx.x;
  const int QE = 73728 / 4;
  if (t >= NE * QE) return;
  int e = t / QE, q = t % QE;
  int j4 = q & 1; q >>= 1;
  int m = q % 192; q /= 192;
  int g = q % 4;   q /= 4;
  int c = q % 6;   q /= 6;
  int h = q;
  int row = h * 192 + m, col = 32 * c + 8 * g + 4 * j4;
  float4 v = *(const float4*)(W + (size_t)e * 73728 + (size_t)row * 192 + col);
  union { _Float16 h4[4]; uint2 u; } cv;
  cv.h4[0] = (_Float16)v.x; cv.h4[1] = (_Float16)v.y;
  cv.h4[2] = (_Float16)v.z; cv.h4[3] = (_Float16)v.w;
  ((uint2*)d)[t] = cv.u;
}

__global__ __launch_bounds__(256) void cvt_w2(const float* __restrict__ W,
                                              _Float16* __restrict__ d) {
  int t = blockIdx.x * 256 + threadIdx.x;
  const int QE = 147456 / 4;
  if (t >= NE * QE) return;
  int e = t / QE, q = t % QE;
  int j4 = q & 1; q >>= 1;
  int m = q % 192; q /= 192;
  int g = q % 4;   q /= 4;
  int mh = q % 2;  q /= 2;
  int c = q % 6;   q /= 6;
  int kh = q;
  int row = mh * 192 + m;
  int col = kh * 192 + 32 * c + 8 * g + 4 * j4;
  float4 v = *(const float4*)(W + (size_t)e * 147456 + (size_t)row * 384 + col);
  union { _Float16 h4[4]; uint2 u; } cv;
  cv.h4[0] = (_Float16)v.x; cv.h4[1] = (_Float16)v.y;
  cv.h4[2] = (_Float16)v.z; cv.h4[3] = (_Float16)v.w;
  ((uint2*)d)[t] = cv.u;
}

__global__ __launch_bounds__(256) void cvt_w3(const float* __restrict__ W,
                                              _Float16* __restrict__ d) {
  int t = blockIdx.x * 256 + threadIdx.x;
  const int QE = 73728 / 4;
  if (t >= NE * QE) return;
  int e = t / QE, q = t % QE;
  int j4 = q & 1; q >>= 1;
  int m = q % 192; q /= 192;
  int g = q % 4;   q /= 4;
  int c = q;                       // 0..11
  int col = 32 * c + 8 * g + 4 * j4;
  float4 v = *(const float4*)(W + (size_t)e * 73728 + (size_t)m * 384 + col);
  union { _Float16 h4[4]; uint2 u; } cv;
  cv.h4[0] = (_Float16)v.x; cv.h4[1] = (_Float16)v.y;
  cv.h4[2] = (_Float16)v.z; cv.h4[3] = (_Float16)v.w;
  ((uint2*)d)[t] = cv.u;
}

// ---------------------------------------------------------------------------
// x transpose for an image pair: x [img][192][16384] fp32 ->
// xt [img2][16384][192] fp16. grid (PPB/64, 2).
// ---------------------------------------------------------------------------
__global__ __launch_bounds__(256) void xt_kernel(const float* __restrict__ x,
                                                 _Float16* __restrict__ xt, int pair) {
  const int img2 = blockIdx.y;
  const float* xb = x + (size_t)(pair * 2 + img2) * IN_C * HW;
  _Float16* dst = xt + (size_t)img2 * PPB * 192;
  const int tid = threadIdx.x;
  const int p = blockIdx.x * 64 + (tid & 63);
  const int cq0 = tid >> 6;
#pragma unroll
  for (int cq = 0; cq < 6; ++cq) {
    int chq = cq * 4 + cq0;
    union { _Float16 h[8]; uint4 u; } pk;
#pragma unroll
    for (int j = 0; j < 8; ++j)
      pk.h[j] = (_Float16)xb[(size_t)(chq * 8 + j) * HW + p];
    *(uint4*)(dst + (size_t)p * 192 + chq * 8) = pk.u;
  }
}

// ---------------------------------------------------------------------------
// Stage one 12KB chunk global -> LDS (global_load_lds; wave-uniform dest).
// ---------------------------------------------------------------------------
__device__ __forceinline__ void stage_chunk(const _Float16* __restrict__ src,
                                            char* lds, int tid) {
  const int wid = tid >> 6;
  const char* g = (const char*)src;
  __builtin_amdgcn_global_load_lds(
      (const __attribute__((address_space(1))) void*)(g + tid * 16),
      (__attribute__((address_space(3))) void*)(lds + wid * 1024), 16, 0, 0);
  if (wid < 4)
    __builtin_amdgcn_global_load_lds(
        (const __attribute__((address_space(1))) void*)(g + 8192 + tid * 16),
        (__attribute__((address_space(3))) void*)(lds + 8192 + wid * 1024), 16, 0, 0);
}

// 2-phase pipeline: stage chunk c+1 (or next layer's chunk 0) while computing
// chunk c; __syncthreads drains the DMA so the staged chunk is ready.
template <typename F>
__device__ __forceinline__ void pipe(const _Float16* __restrict__ src, int nc,
                                     const _Float16* __restrict__ nsrc,
                                     int& cc, char* stg0, char* stg1, int tid, F comp) {
  for (int c = 0; c < nc; ++c) {
    char* nslot = ((cc + 1) & 1) ? stg1 : stg0;
    if (c + 1 < nc) stage_chunk(src + (size_t)(c + 1) * 6144, nslot, tid);
    else if (nsrc)  stage_chunk(nsrc, nslot, tid);
    comp(c, (const _Float16*)((cc & 1) ? stg1 : stg0));
    ++cc;
    __syncthreads();
  }
}

// One kk=32 MFMA step: A from staged chunk [g][192][8], B from LDS slot order
// [k>>3][64][8]. Identical (lane>>4, j)->k map both sides; C/D: col=lane&15,
// row=4*(lane>>4)+reg (HW-verified).
template <int NM, int NT>
__device__ __forceinline__ void mfma_chunk(const _Float16* __restrict__ A,
                                           const _Float16* __restrict__ B, int kb4,
                                           int m0, int nt0,
                                           f32x4 (&acc)[NM][NT], int lane) {
  const int l15 = lane & 15, g = lane >> 4;
  h8_t a[NM], b[NT];
#pragma unroll
  for (int i = 0; i < NM; ++i)
    a[i] = *(const h8_t*)(A + ((size_t)g * 192 + m0 + i * 16 + l15) * 8);
#pragma unroll
  for (int t = 0; t < NT; ++t)
    b[t] = *(const h8_t*)(B + (((size_t)(kb4 + g) * TN) + (nt0 + t) * 16 + l15) * 8);
#pragma unroll
  for (int i = 0; i < NM; ++i)
#pragma unroll
    for (int t = 0; t < NT; ++t)
      acc[i][t] = __builtin_amdgcn_mfma_f32_16x16x32_f16(a[i], b[t], acc[i][t], 0, 0, 0);
}

// gelu + fp16 pack + store to LDS slot order (stride-16 M frags, local rows).
template <int NM, int NT>
__device__ __forceinline__ void act_store(f32x4 (&acc)[NM][NT], const float* __restrict__ bias,
                                          _Float16* __restrict__ Dst, int m0, int nt0, int lane) {
  const int l15 = lane & 15, g = lane >> 4;
#pragma unroll
  for (int i = 0; i < NM; ++i) {
    int rb = m0 + i * 16 + 4 * g;
    float4 bv = *(const float4*)(bias + rb);
#pragma unroll
    for (int t = 0; t < NT; ++t) {
      int n = (nt0 + t) * 16 + l15;
      union { _Float16 h[4]; uint2 u; } cv;
      cv.h[0] = (_Float16)gelu_exact(acc[i][t][0] + bv.x);
      cv.h[1] = (_Float16)gelu_exact(acc[i][t][1] + bv.y);
      cv.h[2] = (_Float16)gelu_exact(acc[i][t][2] + bv.z);
      cv.h[3] = (_Float16)gelu_exact(acc[i][t][3] + bv.w);
      *(uint2*)(Dst + (((size_t)(rb >> 3) * TN) + n) * 8 + (rb & 7)) = cv.u;
    }
  }
}

// gated y -> fp16, dense store into ybuf[pidsl + c]
template <int NM, int NT>
__device__ __forceinline__ void ybuf_store(f32x4 (&acc)[NM][NT], const float* __restrict__ bias,
                                           _Float16* __restrict__ ybuf,
                                           const int* __restrict__ pidsl,
                                           const float* __restrict__ pg,
                                           int npt, int m0, int nt0, int lane) {
  const int l15 = lane & 15, g = lane >> 4;
#pragma unroll
  for (int t = 0; t < NT; ++t) {
    int n = (nt0 + t) * 16 + l15;
    if (n >= npt) continue;
    float gt = pg[n];
    _Float16* yb = ybuf + pidsl[n];
#pragma unroll
    for (int i = 0; i < NM; ++i) {
      int rb = m0 + i * 16 + 4 * g;
      float4 bv = *(const float4*)(bias + rb);
      union { _Float16 h[4]; uint2 u; } cv;
      cv.h[0] = (_Float16)((acc[i][t][0] + bv.x) * gt);
      cv.h[1] = (_Float16)((acc[i][t][1] + bv.y) * gt);
      cv.h[2] = (_Float16)((acc[i][t][2] + bv.z) * gt);
      cv.h[3] = (_Float16)((acc[i][t][3] + bv.w) * gt);
      *(uint2*)(yb + rb) = cv.u;
    }
  }
}

// ---------------------------------------------------------------------------
// Fused 3-layer MLP, 64-pixel tile, 8 waves, weights streamed through a
// 2x12KB LDS double-buffer. 74.5KB LDS -> 2 blocks/CU (latency overlap).
// Phases: L1h0(6) | L2p0(12, alternating M-half) | L1h1(6) | L2p1(12) |
//         H2 store | L3(12).
// Image pair merged: grid (NE, 512), img2 = y>>8, tile = y&255.
// bid%8==expert -> XCD L2 affinity; weights fetched once per pair.
// ---------------------------------------------------------------------------
__global__ __launch_bounds__(512, 2) void moe_mfma_kernel(
    const _Float16* __restrict__ xt,
    const _Float16* __restrict__ W1s, const float* __restrict__ b1,
    const _Float16* __restrict__ W2s, const float* __restrict__ b2,
    const _Float16* __restrict__ W3s, const float* __restrict__ b3,
    const int* __restrict__ counts, const int* __restrict__ lists,
    const float* __restrict__ gatev, _Float16* __restrict__ ybuf, int pair) {
  const int e = blockIdx.x;
  const int img2 = blockIdx.y >> 8;
  const int tile = blockIdx.y & 255;
  const int img = pair * 2 + img2;
  const int cnt = counts[e * 4 + img];
  const int start = tile * TN;
  if (start >= cnt) return;
  const int npt = min(TN, cnt - start);

  __shared__ __align__(16) char smem[73728 + 768];
  _Float16* XB  = (_Float16*)smem;                 // [24][64][8] 24KB
  _Float16* H1a = (_Float16*)(smem + 24576);       // [24][64][8] 24KB
  _Float16* H2  = (_Float16*)smem;                 // [48][64][8] 48KB (alias)
  char* STG0 = smem + 49152;                       // 12KB
  char* STG1 = smem + 61440;                       // 12KB
  int*   pp    = (int*)(smem + 73728);
  int*   pidsl = (int*)(smem + 73728 + 256);
  float* pg    = (float*)(smem + 73728 + 512);

  const int tid = threadIdx.x;
  const int lane = tid & 63;
  const int wid = tid >> 6;
  // wave roles
  const int m1 = (wid >> 1) * 48, n1 = (wid & 1) * 2;  // L1: 4M x 2N (local)
  const int mh2 = wid >> 2, m2l = (wid & 3) * 48;      // L2: M-half + local
  const int m3 = (wid >> 2) * 96, n3 = wid & 3;        // L3: 2M x 4N

  const _Float16* W1e = W1s + (size_t)e * 73728;
  const _Float16* W2e = W2s + (size_t)e * 147456;
  const _Float16* W3e = W3s + (size_t)e * 73728;

  int cc = 0;
  stage_chunk(W1e, STG0, tid);     // prologue: W1 chunk (h0,c0)

  if (tid < TN) {
    int entry = 0; float g = 0.0f;
    if (tid < npt) {
      entry = lists[(e * 4 + img) * PPB + start + tid];
      g     = gatev[(e * 4 + img) * PPB + start + tid];
    }
    int p = entry & (PPB - 1);
    int slot = (entry >> 14) & 1;
    pp[tid] = img2 * PPB + p;
    pidsl[tid] = ((img2 * PPB + p) * 2 + slot) * 192;
    pg[tid] = g;
  }
  __syncthreads();

  // gather xt rows (fp16, 16B chunks) -> XB slot order
  for (int i = tid; i < 24 * TN; i += 512) {   // 3 iterations
    int n = i & 63;
    int c16 = i >> 6;
    uint4 v = {0, 0, 0, 0};
    if (n < npt) v = *(const uint4*)(xt + (size_t)pp[n] * 192 + c16 * 8);
    *(uint4*)(XB + ((size_t)c16 * TN + n) * 8) = v;
  }
  __syncthreads();

  f32x4 acc2[3][4];
#pragma unroll
  for (int i = 0; i < 3; ++i)
#pragma unroll
    for (int t = 0; t < 4; ++t) acc2[i][t] = (f32x4){0.f, 0.f, 0.f, 0.f};
  f32x4 acc1[3][2];

  // ---- L1 half 0 (6 chunks) ----
#pragma unroll
  for (int i = 0; i < 3; ++i)
#pragma unroll
    for (int t = 0; t < 2; ++t) acc1[i][t] = (f32x4){0.f, 0.f, 0.f, 0.f};
  pipe(W1e, 6, W2e, cc, STG0, STG1, tid,
       [&](int c, const _Float16* A) {
         mfma_chunk<3, 2>(A, XB, c * 4, m1, n1, acc1, lane);
       });
  act_store<3, 2>(acc1, b1 + e * HID, H1a, m1, n1, lane);
  __syncthreads();

  // ---- L2 K-part 0 (12 chunks: [c][mh], waves compute their M-half) ----
  pipe(W2e, 12, W1e + 6 * 6144, cc, STG0, STG1, tid,
       [&](int c, const _Float16* A) {
         if ((c & 1) == mh2)
           mfma_chunk<3, 4>(A, H1a, (c >> 1) * 4, m2l, 0, acc2, lane);
       });

  // ---- L1 half 1 (6 chunks) ----
#pragma unroll
  for (int i = 0; i < 3; ++i)
#pragma unroll
    for (int t = 0; t < 2; ++t) acc1[i][t] = (f32x4){0.f, 0.f, 0.f, 0.f};
  pipe(W1e + 6 * 6144, 6, W2e + 12 * 6144, cc, STG0, STG1, tid,
       [&](int c, const _Float16* A) {
         mfma_chunk<3, 2>(A, XB, c * 4, m1, n1, acc1, lane);
       });
  act_store<3, 2>(acc1, b1 + e * HID + 192, H1a, m1, n1, lane);
  __syncthreads();

  // ---- L2 K-part 1 (12 chunks) ----
  pipe(W2e + 12 * 6144, 12, W3e, cc, STG0, STG1, tid,
       [&](int c, const _Float16* A) {
         if ((c & 1) == mh2)
           mfma_chunk<3, 4>(A, H1a, (c >> 1) * 4, m2l, 0, acc2, lane);
       });

  // ---- gelu(acc2) -> H2 (overwrites XB+H1a region; all reads drained) ----
  act_store<3, 4>(acc2, b2 + e * HID, H2, wid * 48, 0, lane);
  __syncthreads();

  // ---- L3 (12 chunks) over H2 ----
  f32x4 acc3[6][1];
#pragma unroll
  for (int i = 0; i < 6; ++i) acc3[i][0] = (f32x4){0.f, 0.f, 0.f, 0.f};
  pipe(W3e, 12, (const _Float16*)nullptr, cc, STG0, STG1, tid,
       [&](int c, const _Float16* A) {
         mfma_chunk<6, 1>(A, H2, c * 4, m3, n3, acc3, lane);
       });

  ybuf_store<6, 1>(acc3, b3 + e * OUT_C, ybuf, pidsl, pg, npt, m3, n3, lane);
}

// ---------------------------------------------------------------------------
// Sum the two gated slot results per pixel, write out coalesced.
// grid (512): img2 = x>>8, 64-pixel group = x&255. Fully overwrites out.
// ---------------------------------------------------------------------------
__global__ __launch_bounds__(256) void sum_kernel(
    const _Float16* __restrict__ ybuf, float* __restrict__ out, int pair) {
  __shared__ float ys[64][193];
  const int tid = threadIdx.x;
  const int img2 = blockIdx.x >> 8;
  const int p0 = (blockIdx.x & 255) * 64;
  const _Float16* yb = ybuf + (size_t)(img2 * PPB + p0) * 2 * 192;

  for (int t = tid; t < 64 * 48; t += 256) {
    int p = t / 48, c4 = t % 48;
    const uint2* y0 = (const uint2*)(yb + (size_t)p * 2 * 192) + c4;
    uint2 u0 = y0[0];
    uint2 u1 = y0[48];
    union { uint2 u; _Float16 h[4]; } a, b;
    a.u = u0; b.u = u1;
#pragma unroll
    for (int j = 0; j < 4; ++j)
      ys[p][c4 * 4 + j] = (float)a.h[j] + (float)b.h[j];
  }
  __syncthreads();

  float* ob = out + (size_t)(pair * 2 + img2) * OUT_C * HW + p0;
  for (int t = tid; t < OUT_C * 64; t += 256) {
    int c = t >> 6, p = t & 63;
    ob[(size_t)c * HW + p] = ys[p][c];
  }
}

extern "C" void kernel_launch(void* const* d_in, const int* in_sizes, int n_in,
                              void* d_out, int out_size, void* d_ws, size_t ws_size,
                              hipStream_t stream) {
  const float* x   = (const float*)d_in[0];
  const float* rin = (const float*)d_in[1];
  const float* rW  = (const float*)d_in[2];
  const float* rb  = (const float*)d_in[3];
  const float* W1  = (const float*)d_in[4];
  const float* b1  = (const float*)d_in[5];
  const float* W2  = (const float*)d_in[6];
  const float* b2  = (const float*)d_in[7];
  const float* W3  = (const float*)d_in[8];
  const float* b3  = (const float*)d_in[9];
  float* out = (float*)d_out;

  // ws: counts 1K | lists 2M | gatev 2M | W 4.7M | ybuf 25.2M | xt 12.6M = 46.5MB
  char* ws = (char*)d_ws;
  int*   counts = (int*)ws;
  int*   lists  = (int*)(ws + 1024);
  float* gatev  = (float*)(ws + 1024 + (size_t)NE * 4 * PPB * 4);
  _Float16* W1s = (_Float16*)(ws + 1024 + 2 * (size_t)NE * 4 * PPB * 4);
  _Float16* W2s = W1s + (size_t)NE * HID * IN_C;
  _Float16* W3s = W2s + (size_t)NE * HID * HID;
  _Float16* ybuf = W3s + (size_t)NE * OUT_C * HID;   // [2*PPB][2][192] fp16
  _Float16* xt = ybuf + (size_t)2 * PPB * 2 * 192;   // [2*PPB][192] fp16

  hipMemsetAsync(counts, 0, NE * 4 * sizeof(int), stream);

  cvt_w1<<<(NE * 73728 / 4 + 255) / 256, 256, 0, stream>>>(W1, W1s);
  cvt_w2<<<(NE * 147456 / 4 + 255) / 256, 256, 0, stream>>>(W2, W2s);
  cvt_w3<<<(NE * 73728 / 4 + 255) / 256, 256, 0, stream>>>(W3, W3s);

  router_kernel<<<NPIX / 256, 256, 0, stream>>>(rin, rW, rb, counts, lists, gatev);

  for (int pair = 0; pair < 2; ++pair) {
    xt_kernel<<<dim3(PPB / 64, 2), 256, 0, stream>>>(x, xt, pair);
    moe_mfma_kernel<<<dim3(NE, 512), 512, 0, stream>>>(
        xt, W1s, b1, W2s, b2, W3s, b3, counts, lists, gatev, ybuf, pair);
    sum_kernel<<<512, 256, 0, stream>>>(ybuf, out, pair);
  }
}

// Round 11
// 268.200 us; speedup vs baseline: 1.5369x; 1.1866x over previous
//
#include <hip/hip_runtime.h>
#include <math.h>

#define NE 8
#define IN_C 192
#define HID 384
#define OUT_C 192
#define R_C 8
#define HW 16384
#define NPIX 65536
#define PPB 16384    // pixels per image
#define TNP 128      // pixels per moe block

typedef _Float16 h8_t __attribute__((ext_vector_type(8)));
typedef float f32x4 __attribute__((ext_vector_type(4)));

// A&S 7.1.26 erf (|abs err| <= 1.5e-7) -> exact-GELU within fp32 noise.
__device__ __forceinline__ float gelu_exact(float v) {
  float z  = v * 0.70710678118654752f;
  float az = fabsf(z);
  float t  = __builtin_amdgcn_rcpf(1.0f + 0.3275911f * az);
  float p  = ((((1.061405429f * t - 1.453152027f) * t + 1.421413741f) * t
               - 0.284496736f) * t + 0.254829592f) * t;
  float er = 1.0f - p * __expf(-z * z);
  er = copysignf(er, z);
  return 0.5f * v * (1.0f + er);
}

// ---------------------------------------------------------------------------
// Router (unchanged): LDS histogram + one global atomicAdd per (block,expert).
// ---------------------------------------------------------------------------
__global__ __launch_bounds__(256) void router_kernel(
    const float* __restrict__ rin, const float* __restrict__ rW,
    const float* __restrict__ rb, int* __restrict__ counts,
    int* __restrict__ lists, float* __restrict__ gatev) {
  const int tid = threadIdx.x;
  const int pid = blockIdx.x * 256 + tid;
  const int img = pid >> 14;
  const int p = pid & (PPB - 1);

  __shared__ int lcount[NE];
  __shared__ int lbase[NE];
  if (tid < NE) lcount[tid] = 0;
  __syncthreads();

  const float* rbase = rin + (size_t)img * R_C * HW + p;
  float r[R_C];
#pragma unroll
  for (int c = 0; c < R_C; ++c) r[c] = rbase[(size_t)c * HW];
  float lg[NE];
#pragma unroll
  for (int e = 0; e < NE; ++e) {
    float s = rb[e];
#pragma unroll
    for (int c = 0; c < R_C; ++c) s += rW[e * R_C + c] * r[c];
    lg[e] = s;
  }
  int e0 = 0; float l0 = lg[0];
#pragma unroll
  for (int e = 1; e < NE; ++e) { if (lg[e] > l0) { l0 = lg[e]; e0 = e; } }
  int e1 = -1; float l1 = -3.4e38f;
#pragma unroll
  for (int e = 0; e < NE; ++e) {
    if (e != e0 && lg[e] > l1) { l1 = lg[e]; e1 = e; }
  }
  float ex  = expf(l1 - l0);
  float inv = 1.0f / (1.0f + ex);
  float g0 = inv, g1 = ex * inv;

  int pos0 = atomicAdd(&lcount[e0], 1);
  int pos1 = atomicAdd(&lcount[e1], 1);
  __syncthreads();
  if (tid < NE) lbase[tid] = atomicAdd(&counts[tid * 4 + img], lcount[tid]);
  __syncthreads();

  int i0 = (e0 * 4 + img) * PPB + lbase[e0] + pos0;
  lists[i0] = p;
  gatev[i0] = g0;
  int i1 = (e1 * 4 + img) * PPB + lbase[e1] + pos1;
  lists[i1] = p | (1 << 14);
  gatev[i1] = g1;
}

// ---------------------------------------------------------------------------
// Weight transforms (unchanged layouts): fp16 A-fragment slot-order 12KB
// chunks [g:4][m:192][j:8], element (m, k0+8g+j).
//   W1: [e][h:2][c:6]   W2: [e][kh:2][c:6][mh:2]   W3: [e][c:12]
// ---------------------------------------------------------------------------
__global__ __launch_bounds__(256) void cvt_w1(const float* __restrict__ W,
                                              _Float16* __restrict__ d) {
  int t = blockIdx.x * 256 + threadIdx.x;
  const int QE = 73728 / 4;
  if (t >= NE * QE) return;
  int e = t / QE, q = t % QE;
  int j4 = q & 1; q >>= 1;
  int m = q % 192; q /= 192;
  int g = q % 4;   q /= 4;
  int c = q % 6;   q /= 6;
  int h = q;
  int row = h * 192 + m, col = 32 * c + 8 * g + 4 * j4;
  float4 v = *(const float4*)(W + (size_t)e * 73728 + (size_t)row * 192 + col);
  union { _Float16 h4[4]; uint2 u; } cv;
  cv.h4[0] = (_Float16)v.x; cv.h4[1] = (_Float16)v.y;
  cv.h4[2] = (_Float16)v.z; cv.h4[3] = (_Float16)v.w;
  ((uint2*)d)[t] = cv.u;
}

__global__ __launch_bounds__(256) void cvt_w2(const float* __restrict__ W,
                                              _Float16* __restrict__ d) {
  int t = blockIdx.x * 256 + threadIdx.x;
  const int QE = 147456 / 4;
  if (t >= NE * QE) return;
  int e = t / QE, q = t % QE;
  int j4 = q & 1; q >>= 1;
  int m = q % 192; q /= 192;
  int g = q % 4;   q /= 4;
  int mh = q % 2;  q /= 2;
  int c = q % 6;   q /= 6;
  int kh = q;
  int row = mh * 192 + m;
  int col = kh * 192 + 32 * c + 8 * g + 4 * j4;
  float4 v = *(const float4*)(W + (size_t)e * 147456 + (size_t)row * 384 + col);
  union { _Float16 h4[4]; uint2 u; } cv;
  cv.h4[0] = (_Float16)v.x; cv.h4[1] = (_Float16)v.y;
  cv.h4[2] = (_Float16)v.z; cv.h4[3] = (_Float16)v.w;
  ((uint2*)d)[t] = cv.u;
}

__global__ __launch_bounds__(256) void cvt_w3(const float* __restrict__ W,
                                              _Float16* __restrict__ d) {
  int t = blockIdx.x * 256 + threadIdx.x;
  const int QE = 73728 / 4;
  if (t >= NE * QE) return;
  int e = t / QE, q = t % QE;
  int j4 = q & 1; q >>= 1;
  int m = q % 192; q /= 192;
  int g = q % 4;   q /= 4;
  int c = q;
  int col = 32 * c + 8 * g + 4 * j4;
  float4 v = *(const float4*)(W + (size_t)e * 73728 + (size_t)m * 384 + col);
  union { _Float16 h4[4]; uint2 u; } cv;
  cv.h4[0] = (_Float16)v.x; cv.h4[1] = (_Float16)v.y;
  cv.h4[2] = (_Float16)v.z; cv.h4[3] = (_Float16)v.w;
  ((uint2*)d)[t] = cv.u;
}

// ---------------------------------------------------------------------------
// x transpose for an image pair.
// ---------------------------------------------------------------------------
__global__ __launch_bounds__(256) void xt_kernel(const float* __restrict__ x,
                                                 _Float16* __restrict__ xt, int pair) {
  const int img2 = blockIdx.y;
  const float* xb = x + (size_t)(pair * 2 + img2) * IN_C * HW;
  _Float16* dst = xt + (size_t)img2 * PPB * 192;
  const int tid = threadIdx.x;
  const int p = blockIdx.x * 64 + (tid & 63);
  const int cq0 = tid >> 6;
#pragma unroll
  for (int cq = 0; cq < 6; ++cq) {
    int chq = cq * 4 + cq0;
    union { _Float16 h[8]; uint4 u; } pk;
#pragma unroll
    for (int j = 0; j < 8; ++j)
      pk.h[j] = (_Float16)xb[(size_t)(chq * 8 + j) * HW + p];
    *(uint4*)(dst + (size_t)p * 192 + chq * 8) = pk.u;
  }
}

// ---------------------------------------------------------------------------
// Stage one 12KB chunk (linear) via global_load_lds. Waves 0-7 cover 8KB
// (1 inst), waves 0-3 cover the last 4KB (2nd inst). Per-stage vmcnt cost:
// wid<4 -> 2, wid>=4 -> 1.
// ---------------------------------------------------------------------------
__device__ __forceinline__ void stage16(const _Float16* __restrict__ src,
                                        char* lds, int tid) {
  const int wid = tid >> 6;
  const char* g = (const char*)src;
  __builtin_amdgcn_global_load_lds(
      (const __attribute__((address_space(1))) void*)(g + tid * 16),
      (__attribute__((address_space(3))) void*)(lds + wid * 1024), 16, 0, 0);
  if (wid < 4)
    __builtin_amdgcn_global_load_lds(
        (const __attribute__((address_space(1))) void*)(g + 8192 + tid * 16),
        (__attribute__((address_space(3))) void*)(lds + 8192 + wid * 1024), 16, 0, 0);
}

// Counted-vmcnt phase entry: own stage-(c) loads done, then barrier (all
// waves' portions done). Chunk c+1 stays in flight. sched_barrier pins order.
__device__ __forceinline__ void pwait(int wid, bool last) {
  if (last)          asm volatile("s_waitcnt vmcnt(0)");
  else if (wid < 4)  asm volatile("s_waitcnt vmcnt(2)");
  else               asm volatile("s_waitcnt vmcnt(1)");
  __builtin_amdgcn_sched_barrier(0);
  __builtin_amdgcn_s_barrier();
  __builtin_amdgcn_sched_barrier(0);
}

// chunk index -> source (compile-time folded under full unroll)
__device__ __forceinline__ const _Float16* chunk_src(
    const _Float16* W1e, const _Float16* W2e, const _Float16* W3e, int cg) {
  if (cg < 6)  return W1e + cg * 6144;
  if (cg < 18) return W2e + (cg - 6) * 6144;
  if (cg < 24) return W1e + 36864 + (cg - 18) * 6144;
  if (cg < 36) return W2e + 73728 + (cg - 24) * 6144;
  return W3e + (cg - 36) * 6144;
}

// One kk=32 MFMA step: A staged chunk [g][192][8], B LDS slot order
// [k>>3][TNP][8]. Identical (g,j)->k map both sides; C/D col=lane&15,
// row=4*(lane>>4)+reg (HW-verified).
template <int NM, int NT>
__device__ __forceinline__ void mfma_chunk(const _Float16* __restrict__ A,
                                           const _Float16* __restrict__ B, int kb4,
                                           int m0, int nt0,
                                           f32x4 (&acc)[NM][NT], int lane) {
  const int l15 = lane & 15, g = lane >> 4;
  h8_t a[NM], b[NT];
#pragma unroll
  for (int i = 0; i < NM; ++i)
    a[i] = *(const h8_t*)(A + ((size_t)g * 192 + m0 + i * 16 + l15) * 8);
#pragma unroll
  for (int t = 0; t < NT; ++t)
    b[t] = *(const h8_t*)(B + (((size_t)(kb4 + g) * TNP) + (nt0 + t) * 16 + l15) * 8);
#pragma unroll
  for (int i = 0; i < NM; ++i)
#pragma unroll
    for (int t = 0; t < NT; ++t)
      acc[i][t] = __builtin_amdgcn_mfma_f32_16x16x32_f16(a[i], b[t], acc[i][t], 0, 0, 0);
}

// gelu + fp16 pack -> LDS slot order (bias from LDS; rows = m0-relative).
template <int NM, int NT>
__device__ __forceinline__ void act_store(f32x4 (&acc)[NM][NT], const float* __restrict__ bias,
                                          _Float16* __restrict__ Dst, int m0, int nt0, int lane) {
  const int l15 = lane & 15, g = lane >> 4;
#pragma unroll
  for (int i = 0; i < NM; ++i) {
    int rb = m0 + i * 16 + 4 * g;
    float4 bv = *(const float4*)(bias + rb);
#pragma unroll
    for (int t = 0; t < NT; ++t) {
      int n = (nt0 + t) * 16 + l15;
      union { _Float16 h[4]; uint2 u; } cv;
      cv.h[0] = (_Float16)gelu_exact(acc[i][t][0] + bv.x);
      cv.h[1] = (_Float16)gelu_exact(acc[i][t][1] + bv.y);
      cv.h[2] = (_Float16)gelu_exact(acc[i][t][2] + bv.z);
      cv.h[3] = (_Float16)gelu_exact(acc[i][t][3] + bv.w);
      *(uint2*)(Dst + (((size_t)(rb >> 3) * TNP) + n) * 8 + (rb & 7)) = cv.u;
    }
  }
}

// gated y -> fp16 dense store into ybuf[pidsl + c]
template <int NM, int NT>
__device__ __forceinline__ void ybuf_store(f32x4 (&acc)[NM][NT], const float* __restrict__ bias,
                                           _Float16* __restrict__ ybuf,
                                           const int* __restrict__ pidsl,
                                           const float* __restrict__ pg,
                                           int npt, int m0, int nt0, int lane) {
  const int l15 = lane & 15, g = lane >> 4;
#pragma unroll
  for (int t = 0; t < NT; ++t) {
    int n = (nt0 + t) * 16 + l15;
    if (n >= npt) continue;
    float gt = pg[n];
    _Float16* yb = ybuf + pidsl[n];
#pragma unroll
    for (int i = 0; i < NM; ++i) {
      int rb = m0 + i * 16 + 4 * g;
      float4 bv = *(const float4*)(bias + rb);
      union { _Float16 h[4]; uint2 u; } cv;
      cv.h[0] = (_Float16)((acc[i][t][0] + bv.x) * gt);
      cv.h[1] = (_Float16)((acc[i][t][1] + bv.y) * gt);
      cv.h[2] = (_Float16)((acc[i][t][2] + bv.z) * gt);
      cv.h[3] = (_Float16)((acc[i][t][3] + bv.w) * gt);
      *(uint2*)(yb + rb) = cv.u;
    }
  }
}

// ---------------------------------------------------------------------------
// Fused 3-layer MLP, 128-pixel tile, 8 waves, 48 uniform 12KB weight chunks
// streamed through a 3-buffer counted-vmcnt pipeline (prefetch distance 2;
// raw s_barrier; vmcnt(0) only at the last chunk).
// Chunks: [0..5] W1h0 | [6..17] W2kh0 ([c][mh]) | [18..23] W1h1 |
//         [24..35] W2kh1 | [36..47] W3.
// Every wave computes every chunk: M-quarter (wid>>1) x N-half (wid&1).
// LDS: XB 48K | H1a 48K (H2 96K aliases both) | 3x12K stage | bias 3.75K.
// ---------------------------------------------------------------------------
__global__ __launch_bounds__(512, 2) void moe_mfma_kernel(
    const _Float16* __restrict__ xt,
    const _Float16* __restrict__ W1s, const float* __restrict__ b1,
    const _Float16* __restrict__ W2s, const float* __restrict__ b2,
    const _Float16* __restrict__ W3s, const float* __restrict__ b3,
    const int* __restrict__ counts, const int* __restrict__ lists,
    const float* __restrict__ gatev, _Float16* __restrict__ ybuf, int pair) {
  const int e = blockIdx.x;
  const int img2 = blockIdx.y >> 7;
  const int tile = blockIdx.y & 127;
  const int img = pair * 2 + img2;
  const int cnt = counts[e * 4 + img];
  const int start = tile * TNP;
  if (start >= cnt) return;
  const int npt = min(TNP, cnt - start);

  __shared__ __align__(16) char smem[140544];
  _Float16* XB  = (_Float16*)smem;                  // [24][128][8] 48K
  _Float16* H1a = (_Float16*)(smem + 49152);        // [24][128][8] 48K
  _Float16* H2  = (_Float16*)smem;                  // [48][128][8] 96K alias
  char* STG0 = smem + 98304;
  char* STG1 = smem + 110592;
  char* STG2 = smem + 122880;
  float* BIAS1 = (float*)(smem + 135168);           // 384
  float* BIAS2 = (float*)(smem + 136704);           // 384
  float* BIAS3 = (float*)(smem + 138240);           // 192
  int*   pp    = (int*)(smem + 139008);
  int*   pidsl = (int*)(smem + 139520);
  float* pg    = (float*)(smem + 140032);
  char* const STGp[3] = {STG0, STG1, STG2};

  const int tid = threadIdx.x;
  const int lane = tid & 63;
  const int wid = tid >> 6;
  const int m0loc = (wid >> 1) * 48;      // M-quarter within a 192-row chunk
  const int nt0 = (wid & 1) * 4;          // N-half (4 x 16 px)

  const _Float16* W1e = W1s + (size_t)e * 73728;
  const _Float16* W2e = W2s + (size_t)e * 147456;
  const _Float16* W3e = W3s + (size_t)e * 73728;

  // ---- prologue: lists, biases, x-gather (vmcnt fully drained after) ----
  if (tid < TNP) {
    int entry = 0; float g = 0.0f;
    if (tid < npt) {
      entry = lists[(e * 4 + img) * PPB + start + tid];
      g     = gatev[(e * 4 + img) * PPB + start + tid];
    }
    int p = entry & (PPB - 1);
    int slot = (entry >> 14) & 1;
    pp[tid] = img2 * PPB + p;
    pidsl[tid] = ((img2 * PPB + p) * 2 + slot) * 192;
    pg[tid] = g;
  }
  for (int i = tid; i < 960; i += 512) {
    if (i < 384) BIAS1[i] = b1[e * HID + i];
    else if (i < 768) BIAS2[i - 384] = b2[e * HID + (i - 384)];
    else BIAS3[i - 768] = b3[e * OUT_C + (i - 768)];
  }
  __syncthreads();

  for (int i = tid; i < 24 * TNP; i += 512) {   // 6 iterations
    int n = i & (TNP - 1);
    int c16 = i >> 7;
    uint4 v = {0, 0, 0, 0};
    if (n < npt) v = *(const uint4*)(xt + (size_t)pp[n] * 192 + c16 * 8);
    *(uint4*)(XB + ((size_t)c16 * TNP + n) * 8) = v;
  }
  __syncthreads();   // drains gather vmem; stage counts are clean from here

  // pipeline prologue: chunks 0,1 in flight
  stage16(chunk_src(W1e, W2e, W3e, 0), STGp[0], tid);
  stage16(chunk_src(W1e, W2e, W3e, 1), STGp[1], tid);

  f32x4 acc1[3][4], acc2[6][4];
#pragma unroll
  for (int i = 0; i < 6; ++i)
#pragma unroll
    for (int t = 0; t < 4; ++t) acc2[i][t] = (f32x4){0.f, 0.f, 0.f, 0.f};

  // ---- seg A: phases 0..5, L1 half0 (rows 0..191) ----
#pragma unroll
  for (int i = 0; i < 3; ++i)
#pragma unroll
    for (int t = 0; t < 4; ++t) acc1[i][t] = (f32x4){0.f, 0.f, 0.f, 0.f};
#pragma unroll
  for (int c = 0; c < 6; ++c) {
    pwait(wid, false);
    stage16(chunk_src(W1e, W2e, W3e, c + 2), STGp[(c + 2) % 3], tid);
    mfma_chunk<3, 4>((const _Float16*)STGp[c % 3], XB, c * 4, m0loc, nt0, acc1, lane);
    if (c == 5) act_store<3, 4>(acc1, BIAS1, H1a, m0loc, nt0, lane);
  }

  // ---- seg B: phases 6..17, L2 kh0 ([c][mh]) ----
#pragma unroll
  for (int s = 0; s < 12; ++s) {
    const int c = 6 + s;
    pwait(wid, false);
    stage16(chunk_src(W1e, W2e, W3e, c + 2), STGp[(c + 2) % 3], tid);
    const int mh = s & 1;
    f32x4 (&a2)[3][4] = *(f32x4(*)[3][4])(&acc2[mh * 3]);
    mfma_chunk<3, 4>((const _Float16*)STGp[c % 3], H1a, (s >> 1) * 4, m0loc, nt0, a2, lane);
  }

  // ---- seg C: phases 18..23, L1 half1 (rows 192..383) ----
#pragma unroll
  for (int i = 0; i < 3; ++i)
#pragma unroll
    for (int t = 0; t < 4; ++t) acc1[i][t] = (f32x4){0.f, 0.f, 0.f, 0.f};
#pragma unroll
  for (int s = 0; s < 6; ++s) {
    const int c = 18 + s;
    pwait(wid, false);
    stage16(chunk_src(W1e, W2e, W3e, c + 2), STGp[(c + 2) % 3], tid);
    mfma_chunk<3, 4>((const _Float16*)STGp[c % 3], XB, s * 4, m0loc, nt0, acc1, lane);
    if (s == 5) act_store<3, 4>(acc1, BIAS1 + 192, H1a, m0loc, nt0, lane);
  }

  // ---- seg D: phases 24..35, L2 kh1 ----
#pragma unroll
  for (int s = 0; s < 12; ++s) {
    const int c = 24 + s;
    pwait(wid, false);
    stage16(chunk_src(W1e, W2e, W3e, c + 2), STGp[(c + 2) % 3], tid);
    const int mh = s & 1;
    f32x4 (&a2)[3][4] = *(f32x4(*)[3][4])(&acc2[mh * 3]);
    mfma_chunk<3, 4>((const _Float16*)STGp[c % 3], H1a, (s >> 1) * 4, m0loc, nt0, a2, lane);
    if (s == 11) {
      // all waves done with H1a reads -> extra barrier -> write H2 (aliases)
      __builtin_amdgcn_sched_barrier(0);
      __builtin_amdgcn_s_barrier();
      __builtin_amdgcn_sched_barrier(0);
      f32x4 (&h0)[3][4] = *(f32x4(*)[3][4])(&acc2[0]);
      f32x4 (&h1)[3][4] = *(f32x4(*)[3][4])(&acc2[3]);
      act_store<3, 4>(h0, BIAS2, H2, m0loc, nt0, lane);
      act_store<3, 4>(h1, BIAS2, H2, 192 + m0loc, nt0, lane);
    }
  }

  // ---- seg E: phases 36..47, L3 (rows 0..191, K=384 over H2) ----
#pragma unroll
  for (int i = 0; i < 3; ++i)
#pragma unroll
    for (int t = 0; t < 4; ++t) acc1[i][t] = (f32x4){0.f, 0.f, 0.f, 0.f};
#pragma unroll
  for (int s = 0; s < 12; ++s) {
    const int c = 36 + s;
    pwait(wid, s == 11);
    if (c + 2 < 48) stage16(chunk_src(W1e, W2e, W3e, c + 2), STGp[(c + 2) % 3], tid);
    mfma_chunk<3, 4>((const _Float16*)STGp[c % 3], H2, s * 4, m0loc, nt0, acc1, lane);
  }

  ybuf_store<3, 4>(acc1, BIAS3, ybuf, pidsl, pg, npt, m0loc, nt0, lane);
}

// ---------------------------------------------------------------------------
// Sum the two gated slot results per pixel, write out coalesced.
// ---------------------------------------------------------------------------
__global__ __launch_bounds__(256) void sum_kernel(
    const _Float16* __restrict__ ybuf, float* __restrict__ out, int pair) {
  __shared__ float ys[64][193];
  const int tid = threadIdx.x;
  const int img2 = blockIdx.x >> 8;
  const int p0 = (blockIdx.x & 255) * 64;
  const _Float16* yb = ybuf + (size_t)(img2 * PPB + p0) * 2 * 192;

  for (int t = tid; t < 64 * 48; t += 256) {
    int p = t / 48, c4 = t % 48;
    const uint2* y0 = (const uint2*)(yb + (size_t)p * 2 * 192) + c4;
    uint2 u0 = y0[0];
    uint2 u1 = y0[48];
    union { uint2 u; _Float16 h[4]; } a, b;
    a.u = u0; b.u = u1;
#pragma unroll
    for (int j = 0; j < 4; ++j)
      ys[p][c4 * 4 + j] = (float)a.h[j] + (float)b.h[j];
  }
  __syncthreads();

  float* ob = out + (size_t)(pair * 2 + img2) * OUT_C * HW + p0;
  for (int t = tid; t < OUT_C * 64; t += 256) {
    int c = t >> 6, p = t & 63;
    ob[(size_t)c * HW + p] = ys[p][c];
  }
}

extern "C" void kernel_launch(void* const* d_in, const int* in_sizes, int n_in,
                              void* d_out, int out_size, void* d_ws, size_t ws_size,
                              hipStream_t stream) {
  const float* x   = (const float*)d_in[0];
  const float* rin = (const float*)d_in[1];
  const float* rW  = (const float*)d_in[2];
  const float* rb  = (const float*)d_in[3];
  const float* W1  = (const float*)d_in[4];
  const float* b1  = (const float*)d_in[5];
  const float* W2  = (const float*)d_in[6];
  const float* b2  = (const float*)d_in[7];
  const float* W3  = (const float*)d_in[8];
  const float* b3  = (const float*)d_in[9];
  float* out = (float*)d_out;

  // ws: counts 1K | lists 2M | gatev 2M | W 4.7M | ybuf 25.2M | xt 12.6M
  char* ws = (char*)d_ws;
  int*   counts = (int*)ws;
  int*   lists  = (int*)(ws + 1024);
  float* gatev  = (float*)(ws + 1024 + (size_t)NE * 4 * PPB * 4);
  _Float16* W1s = (_Float16*)(ws + 1024 + 2 * (size_t)NE * 4 * PPB * 4);
  _Float16* W2s = W1s + (size_t)NE * HID * IN_C;
  _Float16* W3s = W2s + (size_t)NE * HID * HID;
  _Float16* ybuf = W3s + (size_t)NE * OUT_C * HID;   // [2*PPB][2][192] fp16
  _Float16* xt = ybuf + (size_t)2 * PPB * 2 * 192;   // [2*PPB][192] fp16

  hipMemsetAsync(counts, 0, NE * 4 * sizeof(int), stream);

  cvt_w1<<<(NE * 73728 / 4 + 255) / 256, 256, 0, stream>>>(W1, W1s);
  cvt_w2<<<(NE * 147456 / 4 + 255) / 256, 256, 0, stream>>>(W2, W2s);
  cvt_w3<<<(NE * 73728 / 4 + 255) / 256, 256, 0, stream>>>(W3, W3s);

  router_kernel<<<NPIX / 256, 256, 0, stream>>>(rin, rW, rb, counts, lists, gatev);

  for (int pair = 0; pair < 2; ++pair) {
    xt_kernel<<<dim3(PPB / 64, 2), 256, 0, stream>>>(x, xt, pair);
    moe_mfma_kernel<<<dim3(NE, 256), 512, 0, stream>>>(
        xt, W1s, b1, W2s, b2, W3s, b3, counts, lists, gatev, ybuf, pair);
    sum_kernel<<<512, 256, 0, stream>>>(ybuf, out, pair);
  }
}

// Round 12
// 262.616 us; speedup vs baseline: 1.5696x; 1.0213x over previous
//
#include <hip/hip_runtime.h>
#include <math.h>

#define NE 8
#define IN_C 192
#define HID 384
#define OUT_C 192
#define R_C 8
#define HW 16384
#define NPIX 65536
#define PPB 16384    // pixels per image
#define TNP 128      // pixels per moe block

typedef _Float16 h8_t __attribute__((ext_vector_type(8)));
typedef float f32x4 __attribute__((ext_vector_type(4)));

// A&S 7.1.26 erf (|abs err| <= 1.5e-7) -> exact-GELU within fp32 noise.
__device__ __forceinline__ float gelu_exact(float v) {
  float z  = v * 0.70710678118654752f;
  float az = fabsf(z);
  float t  = __builtin_amdgcn_rcpf(1.0f + 0.3275911f * az);
  float p  = ((((1.061405429f * t - 1.453152027f) * t + 1.421413741f) * t
               - 0.284496736f) * t + 0.254829592f) * t;
  float er = 1.0f - p * __expf(-z * z);
  er = copysignf(er, z);
  return 0.5f * v * (1.0f + er);
}

// ---------------------------------------------------------------------------
// Router: LDS histogram + one global atomicAdd per (block, expert).
// Entry = p_local | (slot << 14).
// ---------------------------------------------------------------------------
__global__ __launch_bounds__(256) void router_kernel(
    const float* __restrict__ rin, const float* __restrict__ rW,
    const float* __restrict__ rb, int* __restrict__ counts,
    int* __restrict__ lists, float* __restrict__ gatev) {
  const int tid = threadIdx.x;
  const int pid = blockIdx.x * 256 + tid;
  const int img = pid >> 14;
  const int p = pid & (PPB - 1);

  __shared__ int lcount[NE];
  __shared__ int lbase[NE];
  if (tid < NE) lcount[tid] = 0;
  __syncthreads();

  const float* rbase = rin + (size_t)img * R_C * HW + p;
  float r[R_C];
#pragma unroll
  for (int c = 0; c < R_C; ++c) r[c] = rbase[(size_t)c * HW];
  float lg[NE];
#pragma unroll
  for (int e = 0; e < NE; ++e) {
    float s = rb[e];
#pragma unroll
    for (int c = 0; c < R_C; ++c) s += rW[e * R_C + c] * r[c];
    lg[e] = s;
  }
  int e0 = 0; float l0 = lg[0];
#pragma unroll
  for (int e = 1; e < NE; ++e) { if (lg[e] > l0) { l0 = lg[e]; e0 = e; } }
  int e1 = -1; float l1 = -3.4e38f;
#pragma unroll
  for (int e = 0; e < NE; ++e) {
    if (e != e0 && lg[e] > l1) { l1 = lg[e]; e1 = e; }
  }
  float ex  = expf(l1 - l0);
  float inv = 1.0f / (1.0f + ex);
  float g0 = inv, g1 = ex * inv;

  int pos0 = atomicAdd(&lcount[e0], 1);
  int pos1 = atomicAdd(&lcount[e1], 1);
  __syncthreads();
  if (tid < NE) lbase[tid] = atomicAdd(&counts[tid * 4 + img], lcount[tid]);
  __syncthreads();

  int i0 = (e0 * 4 + img) * PPB + lbase[e0] + pos0;
  lists[i0] = p;
  gatev[i0] = g0;
  int i1 = (e1 * 4 + img) * PPB + lbase[e1] + pos1;
  lists[i1] = p | (1 << 14);
  gatev[i1] = g1;
}

// ---------------------------------------------------------------------------
// Weight transform: fp32 -> fp16 blob, ONE contiguous stream per expert in
// exact consumption order. 48 chunks x 12KB; chunk = [g:4][m:192][j:8],
// element (m, k0 + 8g + j).
// Chunk cg: [0,6) W1 rows 0..191 cols 32cg.. | [6,18) W2 (c=(cg-6)>>1,
// mh=(cg-6)&1) rows 192mh+m cols 32c | [18,24) W1 rows 192+ | [24,36) W2
// cols 192+32c | [36,48) W3.
// ---------------------------------------------------------------------------
__global__ __launch_bounds__(256) void cvt_blob(
    const float* __restrict__ W1, const float* __restrict__ W2,
    const float* __restrict__ W3, _Float16* __restrict__ Wb) {
  int t = blockIdx.x * 256 + threadIdx.x;
  if (t >= NE * 73728) return;     // uint2 units: 48*1536 per expert
  int e = t / 73728, r = t % 73728;
  int cg = r / 1536, w = r % 1536;
  int j4 = w & 1, gm = w >> 1;
  int m = gm % 192, g = gm / 192;
  const float* src; int row, col, lda;
  if (cg < 6)       { src = W1 + (size_t)e * 73728;  row = m;       col = 32 * cg + 8 * g + 4 * j4; lda = 192; }
  else if (cg < 18) { int s = cg - 6;  int c = s >> 1, mh = s & 1;
                      src = W2 + (size_t)e * 147456; row = 192 * mh + m; col = 32 * c + 8 * g + 4 * j4; lda = 384; }
  else if (cg < 24) { int c = cg - 18;
                      src = W1 + (size_t)e * 73728;  row = 192 + m; col = 32 * c + 8 * g + 4 * j4; lda = 192; }
  else if (cg < 36) { int s = cg - 24; int c = s >> 1, mh = s & 1;
                      src = W2 + (size_t)e * 147456; row = 192 * mh + m; col = 192 + 32 * c + 8 * g + 4 * j4; lda = 384; }
  else              { int c = cg - 36;
                      src = W3 + (size_t)e * 73728;  row = m;       col = 32 * c + 8 * g + 4 * j4; lda = 384; }
  float4 v = *(const float4*)(src + (size_t)row * lda + col);
  union { _Float16 h4[4]; uint2 u; } cv;
  cv.h4[0] = (_Float16)v.x; cv.h4[1] = (_Float16)v.y;
  cv.h4[2] = (_Float16)v.z; cv.h4[3] = (_Float16)v.w;
  ((uint2*)Wb)[t] = cv.u;
}

// ---------------------------------------------------------------------------
// x transpose for an image pair.
// ---------------------------------------------------------------------------
__global__ __launch_bounds__(256) void xt_kernel(const float* __restrict__ x,
                                                 _Float16* __restrict__ xt, int pair) {
  const int img2 = blockIdx.y;
  const float* xb = x + (size_t)(pair * 2 + img2) * IN_C * HW;
  _Float16* dst = xt + (size_t)img2 * PPB * 192;
  const int tid = threadIdx.x;
  const int p = blockIdx.x * 64 + (tid & 63);
  const int cq0 = tid >> 6;
#pragma unroll
  for (int cq = 0; cq < 6; ++cq) {
    int chq = cq * 4 + cq0;
    union { _Float16 h[8]; uint4 u; } pk;
#pragma unroll
    for (int j = 0; j < 8; ++j)
      pk.h[j] = (_Float16)xb[(size_t)(chq * 8 + j) * HW + p];
    *(uint4*)(dst + (size_t)p * 192 + chq * 8) = pk.u;
  }
}

// ---------------------------------------------------------------------------
// Weight-stream pipeline state. Quantum = 8KB = exactly 1 global_load_lds per
// wave (512 lanes x 16B) -> vmcnt counts are UNIFORM across waves. Ring = 6
// quanta (48KB) = 4 chunks. Constant vmcnt(3) at phase entry.
// ---------------------------------------------------------------------------
struct Pipe {
  unsigned qi;        // next quantum index (72 total)
  int rslot;          // ring slot 0..5
  int cslot;          // chunk slot of current even chunk (0 or 2)
  const char* wq;     // next quantum's global source
  char* RING;
  int tid, wid;
};

__device__ __forceinline__ void pipe_issue3(Pipe& P) {
#pragma unroll
  for (int k = 0; k < 3; ++k) {
    if (P.qi < 72) {
      __builtin_amdgcn_global_load_lds(
          (const __attribute__((address_space(1))) void*)(P.wq + P.tid * 16),
          (__attribute__((address_space(3))) void*)(P.RING + P.rslot * 8192 + P.wid * 1024),
          16, 0, 0);
      P.wq += 8192;
      P.qi++;
      P.rslot = (P.rslot == 5) ? 0 : P.rslot + 1;
    }
  }
}

// One kk=32 MFMA step: A staged chunk [g][192][8], B LDS slot order
// [k>>3][TNP][8]. Identical (g,j)->k map both sides; C/D col=lane&15,
// row=4*(lane>>4)+reg (HW-verified).
__device__ __forceinline__ void mfma_chunk(const _Float16* __restrict__ A,
                                           const _Float16* __restrict__ B, int kb4,
                                           int m0, int nt0,
                                           f32x4 (&acc)[3][4], int lane) {
  const int l15 = lane & 15, g = lane >> 4;
  h8_t a[3], b[4];
#pragma unroll
  for (int i = 0; i < 3; ++i)
    a[i] = *(const h8_t*)(A + ((size_t)g * 192 + m0 + i * 16 + l15) * 8);
#pragma unroll
  for (int t = 0; t < 4; ++t)
    b[t] = *(const h8_t*)(B + (((size_t)(kb4 + g) * TNP) + (nt0 + t) * 16 + l15) * 8);
#pragma unroll
  for (int i = 0; i < 3; ++i)
#pragma unroll
    for (int t = 0; t < 4; ++t)
      acc[i][t] = __builtin_amdgcn_mfma_f32_16x16x32_f16(a[i], b[t], acc[i][t], 0, 0, 0);
}

// Double-phase: [vmcnt][bar][MFMA 2 chunks][bar][issue 3 quanta].
template <bool LAST, bool DRAIN>
__device__ __forceinline__ void dphase(Pipe& P, const _Float16* __restrict__ Bsh,
                                       int kb0, int kb1,
                                       f32x4 (&accA)[3][4], f32x4 (&accB)[3][4],
                                       int m0loc, int nt0, int lane) {
  if (LAST)       asm volatile("s_waitcnt vmcnt(0)" ::: "memory");
  else if (DRAIN) asm volatile("s_waitcnt vmcnt(3) lgkmcnt(0)" ::: "memory");
  else            asm volatile("s_waitcnt vmcnt(3)" ::: "memory");
  __builtin_amdgcn_sched_barrier(0);
  __builtin_amdgcn_s_barrier();
  __builtin_amdgcn_sched_barrier(0);
  const _Float16* A0 = (const _Float16*)(P.RING + P.cslot * 12288);
  const _Float16* A1 = (const _Float16*)(P.RING + (P.cslot + 1) * 12288);
  __builtin_amdgcn_s_setprio(1);
  mfma_chunk(A0, Bsh, kb0, m0loc, nt0, accA, lane);
  mfma_chunk(A1, Bsh, kb1, m0loc, nt0, accB, lane);
  __builtin_amdgcn_s_setprio(0);
  P.cslot ^= 2;
  if (!LAST) {
    __builtin_amdgcn_sched_barrier(0);
    __builtin_amdgcn_s_barrier();      // consumed slots now free for overwrite
    __builtin_amdgcn_sched_barrier(0);
    pipe_issue3(P);
  }
}

// gelu + fp16 pack -> LDS slot order (rows local to chunk; bias[rb]).
__device__ __forceinline__ void act_store(f32x4 (&acc)[3][4], const float* __restrict__ bias,
                                          _Float16* __restrict__ Dst, int m0, int nt0, int lane) {
  const int l15 = lane & 15, g = lane >> 4;
#pragma unroll
  for (int i = 0; i < 3; ++i) {
    int rb = m0 + i * 16 + 4 * g;
    float4 bv = *(const float4*)(bias + rb);
#pragma unroll
    for (int t = 0; t < 4; ++t) {
      int n = (nt0 + t) * 16 + l15;
      union { _Float16 h[4]; uint2 u; } cv;
      cv.h[0] = (_Float16)gelu_exact(acc[i][t][0] + bv.x);
      cv.h[1] = (_Float16)gelu_exact(acc[i][t][1] + bv.y);
      cv.h[2] = (_Float16)gelu_exact(acc[i][t][2] + bv.z);
      cv.h[3] = (_Float16)gelu_exact(acc[i][t][3] + bv.w);
      *(uint2*)(Dst + (((size_t)(rb >> 3) * TNP) + n) * 8 + (rb & 7)) = cv.u;
    }
  }
}

__device__ __forceinline__ void ybuf_store(f32x4 (&acc)[3][4], const float* __restrict__ bias,
                                           _Float16* __restrict__ ybuf,
                                           const int* __restrict__ pidsl,
                                           const float* __restrict__ pg,
                                           int npt, int m0, int nt0, int lane) {
  const int l15 = lane & 15, g = lane >> 4;
#pragma unroll
  for (int t = 0; t < 4; ++t) {
    int n = (nt0 + t) * 16 + l15;
    if (n >= npt) continue;
    float gt = pg[n];
    _Float16* yb = ybuf + pidsl[n];
#pragma unroll
    for (int i = 0; i < 3; ++i) {
      int rb = m0 + i * 16 + 4 * g;
      float4 bv = *(const float4*)(bias + rb);
      union { _Float16 h[4]; uint2 u; } cv;
      cv.h[0] = (_Float16)((acc[i][t][0] + bv.x) * gt);
      cv.h[1] = (_Float16)((acc[i][t][1] + bv.y) * gt);
      cv.h[2] = (_Float16)((acc[i][t][2] + bv.z) * gt);
      cv.h[3] = (_Float16)((acc[i][t][3] + bv.w) * gt);
      *(uint2*)(yb + rb) = cv.u;
    }
  }
}

// ---------------------------------------------------------------------------
// Fused 3-layer MLP, 128-pixel tile, 8 waves. 24 double-phases over a 48KB
// ring (6x8KB quanta), constant vmcnt(3), 2 barriers/phase, setprio around
// MFMA, rolled segment loops (small I-footprint).
// Segments: A(3dp) L1h0 | B(6dp) L2kh0 | C(3dp) L1h1 | D(6dp) L2kh1 | E(6dp) L3.
// LDS: XB 48K | H1a 48K (H2 96K alias) | RING 48K | bias/misc 5.4K = 152.8K.
// ---------------------------------------------------------------------------
__global__ __launch_bounds__(512, 2) void moe_mfma_kernel(
    const _Float16* __restrict__ xt, const _Float16* __restrict__ Wb,
    const float* __restrict__ b1, const float* __restrict__ b2,
    const float* __restrict__ b3,
    const int* __restrict__ counts, const int* __restrict__ lists,
    const float* __restrict__ gatev, _Float16* __restrict__ ybuf, int pair) {
  const int e = blockIdx.x;
  const int img2 = blockIdx.y >> 7;
  const int tile = blockIdx.y & 127;
  const int img = pair * 2 + img2;
  const int cnt = counts[e * 4 + img];
  const int start = tile * TNP;
  if (start >= cnt) return;
  const int npt = min(TNP, cnt - start);

  __shared__ __align__(16) char smem[152832];
  _Float16* XB  = (_Float16*)smem;                 // [24][128][8] 48K
  _Float16* H1a = (_Float16*)(smem + 49152);       // [24][128][8] 48K
  _Float16* H2  = (_Float16*)smem;                 // [48][128][8] alias
  char* RING   = smem + 98304;                     // 48K
  float* BIAS1 = (float*)(smem + 147456);          // 384
  float* BIAS2 = (float*)(smem + 148992);          // 384
  float* BIAS3 = (float*)(smem + 150528);          // 192
  int*   pp    = (int*)(smem + 151296);
  int*   pidsl = (int*)(smem + 151808);
  float* pg    = (float*)(smem + 152320);

  const int tid = threadIdx.x;
  const int lane = tid & 63;
  const int wid = tid >> 6;
  const int m0loc = (wid >> 1) * 48;
  const int nt0 = (wid & 1) * 4;

  // ---- prologue: lists, biases, x-gather ----
  if (tid < TNP) {
    int entry = 0; float g = 0.0f;
    if (tid < npt) {
      entry = lists[(e * 4 + img) * PPB + start + tid];
      g     = gatev[(e * 4 + img) * PPB + start + tid];
    }
    int p = entry & (PPB - 1);
    int slot = (entry >> 14) & 1;
    pp[tid] = img2 * PPB + p;
    pidsl[tid] = ((img2 * PPB + p) * 2 + slot) * 192;
    pg[tid] = g;
  }
  for (int i = tid; i < 960; i += 512) {
    if (i < 384) BIAS1[i] = b1[e * HID + i];
    else if (i < 768) BIAS2[i - 384] = b2[e * HID + (i - 384)];
    else BIAS3[i - 768] = b3[e * OUT_C + (i - 768)];
  }
  __syncthreads();

  for (int i = tid; i < 24 * TNP; i += 512) {
    int n = i & (TNP - 1);
    int c16 = i >> 7;
    uint4 v = {0, 0, 0, 0};
    if (n < npt) v = *(const uint4*)(xt + (size_t)pp[n] * 192 + c16 * 8);
    *(uint4*)(XB + ((size_t)c16 * TNP + n) * 8) = v;
  }
  __syncthreads();   // drains all prologue vmem: only quanta counted below

  Pipe P{0u, 0, 0, (const char*)(Wb + (size_t)e * 294912), RING, tid, wid};
  pipe_issue3(P);
  pipe_issue3(P);    // quanta 0..5 in flight

  f32x4 acc1[3][4], acc2a[3][4], acc2b[3][4];
#pragma unroll
  for (int i = 0; i < 3; ++i)
#pragma unroll
    for (int t = 0; t < 4; ++t) {
      acc1[i][t] = (f32x4){0.f, 0.f, 0.f, 0.f};
      acc2a[i][t] = (f32x4){0.f, 0.f, 0.f, 0.f};
      acc2b[i][t] = (f32x4){0.f, 0.f, 0.f, 0.f};
    }

  // ---- seg A: L1 half0 ----
#pragma unroll 1
  for (int s = 0; s < 3; ++s)
    dphase<false, false>(P, XB, 8 * s, 8 * s + 4, acc1, acc1, m0loc, nt0, lane);
  act_store(acc1, BIAS1, H1a, m0loc, nt0, lane);

  // ---- seg B: L2 kh0 ----
  dphase<false, true>(P, H1a, 0, 0, acc2a, acc2b, m0loc, nt0, lane);
#pragma unroll 1
  for (int s = 1; s < 6; ++s)
    dphase<false, false>(P, H1a, 4 * s, 4 * s, acc2a, acc2b, m0loc, nt0, lane);

  // ---- seg C: L1 half1 ----
#pragma unroll
  for (int i = 0; i < 3; ++i)
#pragma unroll
    for (int t = 0; t < 4; ++t) acc1[i][t] = (f32x4){0.f, 0.f, 0.f, 0.f};
#pragma unroll 1
  for (int s = 0; s < 3; ++s)
    dphase<false, false>(P, XB, 8 * s, 8 * s + 4, acc1, acc1, m0loc, nt0, lane);
  act_store(acc1, BIAS1 + 192, H1a, m0loc, nt0, lane);

  // ---- seg D: L2 kh1 ----
  dphase<false, true>(P, H1a, 0, 0, acc2a, acc2b, m0loc, nt0, lane);
#pragma unroll 1
  for (int s = 1; s < 6; ++s)
    dphase<false, false>(P, H1a, 4 * s, 4 * s, acc2a, acc2b, m0loc, nt0, lane);
  // all H1a reads done (bar2 of last D phase) -> write H2 (aliases XB+H1a)
  act_store(acc2a, BIAS2, H2, m0loc, nt0, lane);
  act_store(acc2b, BIAS2, H2, 192 + m0loc, nt0, lane);

  // ---- seg E: L3 over H2 ----
#pragma unroll
  for (int i = 0; i < 3; ++i)
#pragma unroll
    for (int t = 0; t < 4; ++t) acc1[i][t] = (f32x4){0.f, 0.f, 0.f, 0.f};
  dphase<false, true>(P, H2, 0, 4, acc1, acc1, m0loc, nt0, lane);
#pragma unroll 1
  for (int s = 1; s < 5; ++s)
    dphase<false, false>(P, H2, 8 * s, 8 * s + 4, acc1, acc1, m0loc, nt0, lane);
  dphase<true, false>(P, H2, 40, 44, acc1, acc1, m0loc, nt0, lane);

  ybuf_store(acc1, BIAS3, ybuf, pidsl, pg, npt, m0loc, nt0, lane);
}

// ---------------------------------------------------------------------------
// Sum the two gated slot results per pixel, write out coalesced.
// ---------------------------------------------------------------------------
__global__ __launch_bounds__(256) void sum_kernel(
    const _Float16* __restrict__ ybuf, float* __restrict__ out, int pair) {
  __shared__ float ys[64][193];
  const int tid = threadIdx.x;
  const int img2 = blockIdx.x >> 8;
  const int p0 = (blockIdx.x & 255) * 64;
  const _Float16* yb = ybuf + (size_t)(img2 * PPB + p0) * 2 * 192;

  for (int t = tid; t < 64 * 48; t += 256) {
    int p = t / 48, c4 = t % 48;
    const uint2* y0 = (const uint2*)(yb + (size_t)p * 2 * 192) + c4;
    uint2 u0 = y0[0];
    uint2 u1 = y0[48];
    union { uint2 u; _Float16 h[4]; } a, b;
    a.u = u0; b.u = u1;
#pragma unroll
    for (int j = 0; j < 4; ++j)
      ys[p][c4 * 4 + j] = (float)a.h[j] + (float)b.h[j];
  }
  __syncthreads();

  float* ob = out + (size_t)(pair * 2 + img2) * OUT_C * HW + p0;
  for (int t = tid; t < OUT_C * 64; t += 256) {
    int c = t >> 6, p = t & 63;
    ob[(size_t)c * HW + p] = ys[p][c];
  }
}

extern "C" void kernel_launch(void* const* d_in, const int* in_sizes, int n_in,
                              void* d_out, int out_size, void* d_ws, size_t ws_size,
                              hipStream_t stream) {
  const float* x   = (const float*)d_in[0];
  const float* rin = (const float*)d_in[1];
  const float* rW  = (const float*)d_in[2];
  const float* rb  = (const float*)d_in[3];
  const float* W1  = (const float*)d_in[4];
  const float* b1  = (const float*)d_in[5];
  const float* W2  = (const float*)d_in[6];
  const float* b2  = (const float*)d_in[7];
  const float* W3  = (const float*)d_in[8];
  const float* b3  = (const float*)d_in[9];
  float* out = (float*)d_out;

  // ws: counts 1K | lists 2M | gatev 2M | Wblob 4.5M | ybuf 25.2M | xt 12.6M
  char* ws = (char*)d_ws;
  int*   counts = (int*)ws;
  int*   lists  = (int*)(ws + 1024);
  float* gatev  = (float*)(ws + 1024 + (size_t)NE * 4 * PPB * 4);
  _Float16* Wb  = (_Float16*)(ws + 1024 + 2 * (size_t)NE * 4 * PPB * 4);
  _Float16* ybuf = Wb + (size_t)NE * 294912;         // [2*PPB][2][192] fp16
  _Float16* xt = ybuf + (size_t)2 * PPB * 2 * 192;   // [2*PPB][192] fp16

  hipMemsetAsync(counts, 0, NE * 4 * sizeof(int), stream);

  cvt_blob<<<(NE * 73728 + 255) / 256, 256, 0, stream>>>(W1, W2, W3, Wb);

  router_kernel<<<NPIX / 256, 256, 0, stream>>>(rin, rW, rb, counts, lists, gatev);

  for (int pair = 0; pair < 2; ++pair) {
    xt_kernel<<<dim3(PPB / 64, 2), 256, 0, stream>>>(x, xt, pair);
    moe_mfma_kernel<<<dim3(NE, 256), 512, 0, stream>>>(
        xt, Wb, b1, b2, b3, counts, lists, gatev, ybuf, pair);
    sum_kernel<<<512, 256, 0, stream>>>(ybuf, out, pair);
  }
}